// Round 7
// baseline (256.322 us; speedup 1.0000x reference)
//
#include <hip/hip_runtime.h>
#include <stdint.h>

#define BATCH 8
#define NN 262144
#define K_PRE 6000
#define NPROP 1000
#define NMS_THR 0.7f
#define CAND_CAP 8192
#define PREFIX 2048
#define NB1 16384
#define NB2 4096

// meta u32 indices
#define MT_T2 0        // [0..7]   final threshold (read-only after thresh2)
#define MT_KEPT 16     // [16..23] kept count per batch
#define MT_T1 24       // [24..31] coarse bucket
#define MT_CUM 32      // [32..39] cum count above coarse bucket
#define MT_CNT(b) (64 + 32*(b))   // padded counters, 128B apart

// workspace layout (bytes)
#define HIST1_OFF 0                                   // BATCH*NB1*4 = 524288
#define HIST2_OFF (HIST1_OFF + BATCH*NB1*4)           // + BATCH*NB2*4 = 131072
#define META_OFF  (HIST2_OFF + BATCH*NB2*4)           // 2048 B
#define CAND_OFF  (META_OFF + 2048)
#define BOXES_OFF (CAND_OFF + BATCH*CAND_CAP*8)       // BATCH*K_PRE*16
#define MASK_OFF  (BOXES_OFF + BATCH*K_PRE*16)        // BATCH*PREFIX*64*4 = 4 MB
#define KIDX_OFF  (MASK_OFF + (size_t)BATCH*PREFIX*64*4)
#define WS_NEED   (KIDX_OFF + BATCH*NPROP*4)

#define HZERO (BATCH * (NB1 + NB2))                   // u32s of histograms
#define CZERO (BATCH * CAND_CAP * 2)                  // u32s of cand

__device__ __forceinline__ uint32_t fkey(float f) {
    uint32_t b = __float_as_uint(f);
    return b ^ (uint32_t)(((int32_t)b >> 31) | 0x80000000u);
}

// zero the histograms AND the candidate array (pads must be 0 for ranking)
__global__ void k_zero(uint32_t* h, uint32_t* c32) {
    const int i = blockIdx.x * 256 + threadIdx.x;
    if (i < HZERO) h[i] = 0;
    else if (i < HZERO + CZERO) c32[i - HZERO] = 0;
}

// 512 blocks = 64 per batch; each block: 2048 float4 (= 4096 elements).
__global__ __launch_bounds__(256) void k_hist(const float4* __restrict__ probs4,
                                              uint32_t* __restrict__ hist) {
    __shared__ uint32_t h[NB1];
    for (int i = threadIdx.x; i < NB1; i += 256) h[i] = 0;
    __syncthreads();
    const int b = blockIdx.x >> 6;
    const int s = blockIdx.x & 63;
    const float4* p = probs4 + (size_t)b * (NN / 2) + (size_t)s * 2048;
    for (int i = threadIdx.x; i < 2048; i += 256) {
        const float4 v = p[i];
        atomicAdd(&h[fkey(v.y) >> 18], 1u);
        atomicAdd(&h[fkey(v.w) >> 18], 1u);
    }
    __syncthreads();
    uint32_t* gh = hist + (size_t)b * NB1;
    for (int i = threadIdx.x; i < NB1; i += 256)
        if (h[i]) atomicAdd(&gh[i], h[i]);
}

__global__ __launch_bounds__(256) void k_thresh(const uint32_t* __restrict__ hist,
                                                uint32_t* meta) {
    const int b = blockIdx.x;
    const uint32_t* gh = hist + (size_t)b * NB1;
    __shared__ uint32_t part[256];
    const int t = threadIdx.x;
    uint32_t s = 0;
    const int hi = NB1 - 64 * t;
    for (int i = hi - 64; i < hi; ++i) s += gh[i];
    part[t] = s;
    __syncthreads();
    if (t == 0) {
        uint32_t cum = 0;
        int strip = 0;
        for (; strip < 256; ++strip) {
            if (cum + part[strip] >= (uint32_t)K_PRE) break;
            cum += part[strip];
        }
        int t1 = 0;
        if (strip < 256) {
            const int top = NB1 - 64 * strip;
            int i = top - 1;
            for (; i >= top - 64; --i) {
                const uint32_t c = gh[i];
                if (cum + c >= (uint32_t)K_PRE) break;
                cum += c;
            }
            if (i < top - 64) i = top - 64;
            t1 = i;
        }
        meta[MT_T1 + b] = (uint32_t)t1;
        meta[MT_CUM + b] = cum;  // count strictly above bucket t1
    }
}

// 2048 blocks = 256 per batch; ~8k matches per batch spread over 4096 buckets.
__global__ __launch_bounds__(256) void k_hist2(const float4* __restrict__ probs4,
                                               const uint32_t* __restrict__ meta,
                                               uint32_t* __restrict__ hist2) {
    const int b = blockIdx.x >> 8;
    const int s = blockIdx.x & 255;
    const uint32_t t1 = meta[MT_T1 + b];
    const float4* p = probs4 + (size_t)b * (NN / 2) + (size_t)s * 512;
    uint32_t* gh = hist2 + (size_t)b * NB2;
    for (int i = threadIdx.x; i < 512; i += 256) {
        const float4 v = p[i];
        const uint32_t u1 = fkey(v.y);
        const uint32_t u2 = fkey(v.w);
        if ((u1 >> 18) == t1) atomicAdd(&gh[(u1 >> 6) & 0xFFFu], 1u);
        if ((u2 >> 18) == t1) atomicAdd(&gh[(u2 >> 6) & 0xFFFu], 1u);
    }
}

__global__ __launch_bounds__(256) void k_thresh2(const uint32_t* __restrict__ hist2,
                                                 uint32_t* meta) {
    const int b = blockIdx.x;
    const uint32_t* gh = hist2 + (size_t)b * NB2;
    __shared__ uint32_t part[256];
    const int t = threadIdx.x;
    uint32_t s = 0;
    const int hi = NB2 - 16 * t;
    for (int i = hi - 16; i < hi; ++i) s += gh[i];
    part[t] = s;
    __syncthreads();
    if (t == 0) {
        const uint32_t t1 = meta[MT_T1 + b];
        uint32_t cum = meta[MT_CUM + b];
        int strip = 0;
        for (; strip < 256; ++strip) {
            if (cum + part[strip] >= (uint32_t)K_PRE) break;
            cum += part[strip];
        }
        int sub = 0;
        if (strip < 256) {
            const int top = NB2 - 16 * strip;
            int i = top - 1;
            for (; i >= top - 16; --i) {
                const uint32_t c = gh[i];
                if (cum + c >= (uint32_t)K_PRE) break;
                cum += c;
            }
            if (i < top - 16) i = top - 16;
            sub = i;
        }
        meta[MT_T2 + b] = (t1 << 18) | ((uint32_t)sub << 6);
        meta[MT_CNT(b)] = 0;
        meta[MT_KEPT + b] = 0;
    }
}

// 2048 blocks = 256 per batch. Contention-free: LDS stash + ONE padded global
// atomic per block. cand[] slot order is irrelevant (rank pass is order-free).
__global__ __launch_bounds__(256) void k_compact(const float4* __restrict__ probs4,
                                                 const uint32_t* __restrict__ meta,
                                                 uint32_t* cnt_meta, uint64_t* __restrict__ cand) {
    __shared__ uint64_t stash[1024];
    __shared__ uint32_t lcnt, lbase;
    const int b = blockIdx.x >> 8;
    const int s = blockIdx.x & 255;
    const uint32_t T = meta[MT_T2 + b];
    if (threadIdx.x == 0) lcnt = 0;
    __syncthreads();
    const float4* p = probs4 + (size_t)b * (NN / 2) + (size_t)s * 512;
    const uint32_t base_n = (uint32_t)s * 1024;
    for (int i = threadIdx.x; i < 512; i += 256) {
        const float4 v = p[i];
        const uint32_t u1 = fkey(v.y);
        const uint32_t u2 = fkey(v.w);
        if (u1 >= T) {
            const uint32_t pos = atomicAdd(&lcnt, 1u);
            const uint32_t n = base_n + 2u * (uint32_t)i;
            stash[pos] = ((uint64_t)u1 << 32) | (uint32_t)(~n);
        }
        if (u2 >= T) {
            const uint32_t pos = atomicAdd(&lcnt, 1u);
            const uint32_t n = base_n + 2u * (uint32_t)i + 1u;
            stash[pos] = ((uint64_t)u2 << 32) | (uint32_t)(~n);
        }
    }
    __syncthreads();
    if (threadIdx.x == 0) lbase = atomicAdd(&cnt_meta[MT_CNT(b)], lcnt);
    __syncthreads();
    uint64_t* cb = cand + (size_t)b * CAND_CAP;
    const uint32_t n_loc = lcnt, base = lbase;
    for (uint32_t i = threadIdx.x; i < n_loc; i += 256) {
        const uint32_t pos = base + i;
        if (pos < CAND_CAP) cb[pos] = stash[i];
    }
}

// Rank-by-counting replaces the sort: rank_i = #{j : key_j > key_i}.
// Keys are distinct (low 32 bits = ~anchor_index), pads are 0 and rank >= m,
// so ranks of valid keys are a permutation of 0..m-1 -> write boxes[rank].
// grid = BATCH * 32 blocks (all 256 CUs), 256 threads, 1 key per thread.
__global__ __launch_bounds__(256) void k_rankdecode(const uint64_t* __restrict__ cand,
        const uint32_t* __restrict__ meta,
        const float4* __restrict__ bbox, const float4* __restrict__ anch,
        float4* __restrict__ boxes) {
    __shared__ uint64_t jk[CAND_CAP];   // 64 KB
    const int b = blockIdx.x >> 5;
    const uint32_t m = min(meta[MT_CNT(b)], (uint32_t)CAND_CAP);
    const uint64_t* cb = cand + (size_t)b * CAND_CAP;
    for (int j = threadIdx.x; j < CAND_CAP; j += 256) jk[j] = cb[j];
    __syncthreads();
    const int i = ((blockIdx.x & 31) << 8) + threadIdx.x;
    const uint64_t ki = jk[i];
    uint32_t rank = 0;
#pragma unroll 16
    for (int j = 0; j < CAND_CAP; ++j) rank += (jk[j] > ki) ? 1u : 0u;
    if (i < (int)m && rank < (uint32_t)K_PRE) {
        const uint32_t n = ~((uint32_t)ki);
        const float4 a = anch[(size_t)b * NN + n];
        const float4 d = bbox[(size_t)b * NN + n];
        float h = a.z - a.x, w = a.w - a.y;
        const float cy0 = a.x + 0.5f * h + d.x * 0.1f * h;
        const float cx0 = a.y + 0.5f * w + d.y * 0.1f * w;
        h = h * expf(d.z * 0.2f);
        w = w * expf(d.w * 0.2f);
        float4 o;
        o.x = fminf(fmaxf(cy0 - 0.5f * h, 0.0f), 1.0f);
        o.y = fminf(fmaxf(cx0 - 0.5f * w, 0.0f), 1.0f);
        o.z = fminf(fmaxf(cy0 + 0.5f * h, 0.0f), 1.0f);
        o.w = fminf(fmaxf(cx0 + 0.5f * w, 0.0f), 1.0f);
        boxes[(size_t)b * K_PRE + rank] = o;
    }
}

__global__ __launch_bounds__(256) void k_matrix(const float4* __restrict__ boxes,
                                                uint32_t* __restrict__ mask) {
    const int blk = blockIdx.x;
    const int b = blk >> 10;
    const int tile = blk & 1023;
    const int ti = tile >> 5, tj = tile & 31;
    __shared__ float4 rb[64], cb[64];
    __shared__ uint32_t wbits[128];
    const float4* bx = boxes + (size_t)b * K_PRE;
    const int t = threadIdx.x;
    if (t < 64) rb[t] = bx[ti * 64 + t];
    else if (t < 128) cb[t - 64] = bx[tj * 64 + (t - 64)];
    if (t < 128) wbits[t] = 0;
    __syncthreads();
    const int r = t >> 2;
    const int cq = t & 3;
    const float4 a = rb[r];
    const float areaA = (a.z - a.x) * (a.w - a.y);
    uint32_t bits = 0;
#pragma unroll
    for (int jj = 0; jj < 16; ++jj) {
        const float4 cc = cb[cq * 16 + jj];
        const float yy1 = fmaxf(a.x, cc.x), xx1 = fmaxf(a.y, cc.y);
        const float yy2 = fminf(a.z, cc.z), xx2 = fminf(a.w, cc.w);
        const float inter = fmaxf(yy2 - yy1, 0.0f) * fmaxf(xx2 - xx1, 0.0f);
        const float areaC = (cc.z - cc.x) * (cc.w - cc.y);
        const float uni = fmaxf(areaA + areaC - inter, 1e-8f);
        if (inter / uni > NMS_THR) bits |= (1u << jj);
    }
    atomicOr(&wbits[r * 2 + (cq >> 1)], bits << ((cq & 1) * 16));
    __syncthreads();
    if (t < 128) {
        const int rr = t >> 1, ww = t & 1;
        mask[((size_t)b * PREFIX + ti * 64 + rr) * 64 + tj * 2 + ww] = wbits[rr * 2 + ww];
    }
}

// Greedy NMS bit-scan over the 2048x2048 suppression matrix.
__global__ __launch_bounds__(256) void k_greedy(const uint32_t* __restrict__ mask,
                                                uint32_t* meta, uint32_t* __restrict__ kept_idx) {
    __shared__ uint32_t lbuf[2][256 * 64];   // 2 x 64 KB
    __shared__ uint32_t skept[8];
    const int b = blockIdx.x;
    const int lane = threadIdx.x & 63;
    const int wave = threadIdx.x >> 6;
    const uint32_t* mrow = mask + (size_t)b * PREFIX * 64;

    {
        const uint4* s4 = (const uint4*)mrow;
        uint4* d4 = (uint4*)lbuf[0];
        for (int idx = threadIdx.x; idx < 4096; idx += 256) d4[idx] = s4[idx];
    }
    __syncthreads();

    uint32_t supp = 0;   // lane l: suppression bits for columns [32l, 32l+32)
    uint32_t kept = 0;

    for (int c = 0; c < PREFIX / 256; ++c) {
        if (wave > 0) {
            if (c + 1 < PREFIX / 256) {
                const uint4* s4 = (const uint4*)(mrow + (size_t)(c + 1) * 256 * 64);
                uint4* d4 = (uint4*)lbuf[(c + 1) & 1];
                for (int idx = threadIdx.x - 64; idx < 4096; idx += 192) d4[idx] = s4[idx];
            }
        } else {
            const uint32_t* L = lbuf[c & 1];
            for (int g = 0; g < 8; ++g) {
                if (kept >= NPROP) break;
                const int grow = c * 256 + g * 32;
                const int w = grow >> 5;
                uint32_t rbuf[32];
#pragma unroll
                for (int q = 0; q < 32; ++q) rbuf[q] = L[(g * 32 + q) * 64 + lane];
                uint32_t sw = __builtin_amdgcn_readlane(supp, w);
#pragma unroll
                for (int q = 0; q < 32; ++q) {
                    if (kept < NPROP && !((sw >> q) & 1u)) {
                        if (lane == 0) kept_idx[(size_t)b * NPROP + kept] = (uint32_t)(grow + q);
                        supp |= rbuf[q];
                        sw |= __builtin_amdgcn_readlane(rbuf[q], w);
                        ++kept;
                    }
                }
            }
            if (lane == 0) skept[c] = kept;
        }
        __syncthreads();
        if (skept[c] >= NPROP) break;
    }
    if (wave == 0 && lane == 0) meta[MT_KEPT + b] = kept;
}

__global__ __launch_bounds__(1024) void k_finish(const float4* __restrict__ boxes,
        uint32_t* meta, uint32_t* kept_idx, float4* __restrict__ out) {
    const int b = blockIdx.x;
    const float4* bx = boxes + (size_t)b * K_PRE;
    __shared__ float4 kb[NPROP];
    __shared__ uint32_t sflag;
    uint32_t kept = meta[MT_KEPT + b];
    if (kept < NPROP) {
        for (uint32_t k = threadIdx.x; k < kept; k += 1024)
            kb[k] = bx[kept_idx[(size_t)b * NPROP + k]];
        __syncthreads();
        for (int i = PREFIX; i < K_PRE && kept < NPROP; ++i) {
            if (threadIdx.x == 0) sflag = 0;
            __syncthreads();
            const float4 c = bx[i];
            const float areaC = (c.z - c.x) * (c.w - c.y);
            bool sup = false;
            for (uint32_t k = threadIdx.x; k < kept; k += 1024) {
                const float4 a = kb[k];
                const float yy1 = fmaxf(c.x, a.x), xx1 = fmaxf(c.y, a.y);
                const float yy2 = fminf(c.z, a.z), xx2 = fminf(c.w, a.w);
                const float inter = fmaxf(yy2 - yy1, 0.0f) * fmaxf(xx2 - xx1, 0.0f);
                const float areaA = (a.z - a.x) * (a.w - a.y);
                const float uni = fmaxf(areaC + areaA - inter, 1e-8f);
                if (inter / uni > NMS_THR) { sup = true; break; }
            }
            if (sup) atomicOr(&sflag, 1u);
            __syncthreads();
            if (sflag == 0) {
                if (threadIdx.x == 0) {
                    kept_idx[(size_t)b * NPROP + kept] = (uint32_t)i;
                    kb[kept] = c;
                }
                ++kept;
            }
            __syncthreads();
        }
        if (threadIdx.x == 0) meta[MT_KEPT + b] = kept;
    }
    __syncthreads();
    for (uint32_t k = threadIdx.x; k < NPROP; k += 1024) {
        float4 v = make_float4(0.f, 0.f, 0.f, 0.f);
        if (k < kept) v = bx[kept_idx[(size_t)b * NPROP + k]];
        out[(size_t)b * NPROP + k] = v;
    }
}

extern "C" void kernel_launch(void* const* d_in, const int* in_sizes, int n_in,
                              void* d_out, int out_size, void* d_ws, size_t ws_size,
                              hipStream_t stream) {
    const float4* probs4 = (const float4*)d_in[0];
    const float4* bbox   = (const float4*)d_in[1];
    const float4* anch   = (const float4*)d_in[2];
    char* ws = (char*)d_ws;
    if (ws_size < (size_t)WS_NEED) return;
    uint32_t* hist1 = (uint32_t*)(ws + HIST1_OFF);
    uint32_t* hist2 = (uint32_t*)(ws + HIST2_OFF);
    uint32_t* meta  = (uint32_t*)(ws + META_OFF);
    uint64_t* cand  = (uint64_t*)(ws + CAND_OFF);
    float4*   boxes = (float4*)(ws + BOXES_OFF);
    uint32_t* mask  = (uint32_t*)(ws + MASK_OFF);
    uint32_t* kidx  = (uint32_t*)(ws + KIDX_OFF);

    k_zero<<<dim3((HZERO + CZERO + 255) / 256), dim3(256), 0, stream>>>(hist1, (uint32_t*)cand);
    k_hist<<<dim3(512), dim3(256), 0, stream>>>(probs4, hist1);
    k_thresh<<<dim3(BATCH), dim3(256), 0, stream>>>(hist1, meta);
    k_hist2<<<dim3(2048), dim3(256), 0, stream>>>(probs4, meta, hist2);
    k_thresh2<<<dim3(BATCH), dim3(256), 0, stream>>>(hist2, meta);
    k_compact<<<dim3(2048), dim3(256), 0, stream>>>(probs4, meta, meta, cand);
    k_rankdecode<<<dim3(BATCH * 32), dim3(256), 0, stream>>>(cand, meta, bbox, anch, boxes);
    k_matrix<<<dim3(BATCH * 1024), dim3(256), 0, stream>>>(boxes, mask);
    k_greedy<<<dim3(BATCH), dim3(256), 0, stream>>>(mask, meta, kidx);
    k_finish<<<dim3(BATCH), dim3(1024), 0, stream>>>(boxes, meta, kidx, (float4*)d_out);
}

// Round 8
// 205.605 us; speedup vs baseline: 1.2467x; 1.2467x over previous
//
#include <hip/hip_runtime.h>
#include <stdint.h>

#define BATCH 8
#define NN 262144
#define K_PRE 6000
#define NPROP 1000
#define NMS_THR 0.7f
#define CAND_CAP 8192
#define PREFIX 2048
#define NB1 16384
#define NB2 4096

// meta u32 indices
#define MT_T2 0        // [0..7]   final threshold (read-only after thresh2)
#define MT_KEPT 16     // [16..23] kept count per batch
#define MT_T1 24       // [24..31] coarse bucket
#define MT_CUM 32      // [32..39] cum count above coarse bucket
#define MT_CNT(b) (64 + 32*(b))   // padded counters, 128B apart

// workspace layout (bytes)
#define HIST1_OFF 0                                   // BATCH*NB1*4 = 524288
#define HIST2_OFF (HIST1_OFF + BATCH*NB1*4)           // + BATCH*NB2*4 = 131072
#define META_OFF  (HIST2_OFF + BATCH*NB2*4)           // 2048 B
#define CAND_OFF  (META_OFF + 2048)
#define BOXES_OFF (CAND_OFF + BATCH*CAND_CAP*8)       // BATCH*K_PRE*16
#define MASK_OFF  (BOXES_OFF + BATCH*K_PRE*16)        // BATCH*PREFIX*64*4 = 4 MB
#define KIDX_OFF  (MASK_OFF + (size_t)BATCH*PREFIX*64*4)
#define WS_NEED   (KIDX_OFF + BATCH*NPROP*4)

// rank partials REUSE the mask region (4MB, written later by k_matrix):
// partial[(b*16 + jc)*8192 + i], BATCH*16*8192*4 = 4 MB exactly.

#define HZERO (BATCH * (NB1 + NB2))                   // u32s of histograms
#define CZERO (BATCH * CAND_CAP * 2)                  // u32s of cand

__device__ __forceinline__ uint32_t fkey(float f) {
    uint32_t b = __float_as_uint(f);
    return b ^ (uint32_t)(((int32_t)b >> 31) | 0x80000000u);
}

// zero the histograms AND the candidate array (pads must be 0 for ranking)
__global__ void k_zero(uint32_t* h, uint32_t* c32) {
    const int i = blockIdx.x * 256 + threadIdx.x;
    if (i < HZERO) h[i] = 0;
    else if (i < HZERO + CZERO) c32[i - HZERO] = 0;
}

// 512 blocks = 64 per batch; each block: 2048 float4 (= 4096 elements).
__global__ __launch_bounds__(256) void k_hist(const float4* __restrict__ probs4,
                                              uint32_t* __restrict__ hist) {
    __shared__ uint32_t h[NB1];
    for (int i = threadIdx.x; i < NB1; i += 256) h[i] = 0;
    __syncthreads();
    const int b = blockIdx.x >> 6;
    const int s = blockIdx.x & 63;
    const float4* p = probs4 + (size_t)b * (NN / 2) + (size_t)s * 2048;
    for (int i = threadIdx.x; i < 2048; i += 256) {
        const float4 v = p[i];
        atomicAdd(&h[fkey(v.y) >> 18], 1u);
        atomicAdd(&h[fkey(v.w) >> 18], 1u);
    }
    __syncthreads();
    uint32_t* gh = hist + (size_t)b * NB1;
    for (int i = threadIdx.x; i < NB1; i += 256)
        if (h[i]) atomicAdd(&gh[i], h[i]);
}

__global__ __launch_bounds__(256) void k_thresh(const uint32_t* __restrict__ hist,
                                                uint32_t* meta) {
    const int b = blockIdx.x;
    const uint32_t* gh = hist + (size_t)b * NB1;
    __shared__ uint32_t part[256];
    const int t = threadIdx.x;
    uint32_t s = 0;
    const int hi = NB1 - 64 * t;
    for (int i = hi - 64; i < hi; ++i) s += gh[i];
    part[t] = s;
    __syncthreads();
    if (t == 0) {
        uint32_t cum = 0;
        int strip = 0;
        for (; strip < 256; ++strip) {
            if (cum + part[strip] >= (uint32_t)K_PRE) break;
            cum += part[strip];
        }
        int t1 = 0;
        if (strip < 256) {
            const int top = NB1 - 64 * strip;
            int i = top - 1;
            for (; i >= top - 64; --i) {
                const uint32_t c = gh[i];
                if (cum + c >= (uint32_t)K_PRE) break;
                cum += c;
            }
            if (i < top - 64) i = top - 64;
            t1 = i;
        }
        meta[MT_T1 + b] = (uint32_t)t1;
        meta[MT_CUM + b] = cum;  // count strictly above bucket t1
    }
}

// 2048 blocks = 256 per batch; ~8k matches per batch spread over 4096 buckets.
__global__ __launch_bounds__(256) void k_hist2(const float4* __restrict__ probs4,
                                               const uint32_t* __restrict__ meta,
                                               uint32_t* __restrict__ hist2) {
    const int b = blockIdx.x >> 8;
    const int s = blockIdx.x & 255;
    const uint32_t t1 = meta[MT_T1 + b];
    const float4* p = probs4 + (size_t)b * (NN / 2) + (size_t)s * 512;
    uint32_t* gh = hist2 + (size_t)b * NB2;
    for (int i = threadIdx.x; i < 512; i += 256) {
        const float4 v = p[i];
        const uint32_t u1 = fkey(v.y);
        const uint32_t u2 = fkey(v.w);
        if ((u1 >> 18) == t1) atomicAdd(&gh[(u1 >> 6) & 0xFFFu], 1u);
        if ((u2 >> 18) == t1) atomicAdd(&gh[(u2 >> 6) & 0xFFFu], 1u);
    }
}

__global__ __launch_bounds__(256) void k_thresh2(const uint32_t* __restrict__ hist2,
                                                 uint32_t* meta) {
    const int b = blockIdx.x;
    const uint32_t* gh = hist2 + (size_t)b * NB2;
    __shared__ uint32_t part[256];
    const int t = threadIdx.x;
    uint32_t s = 0;
    const int hi = NB2 - 16 * t;
    for (int i = hi - 16; i < hi; ++i) s += gh[i];
    part[t] = s;
    __syncthreads();
    if (t == 0) {
        const uint32_t t1 = meta[MT_T1 + b];
        uint32_t cum = meta[MT_CUM + b];
        int strip = 0;
        for (; strip < 256; ++strip) {
            if (cum + part[strip] >= (uint32_t)K_PRE) break;
            cum += part[strip];
        }
        int sub = 0;
        if (strip < 256) {
            const int top = NB2 - 16 * strip;
            int i = top - 1;
            for (; i >= top - 16; --i) {
                const uint32_t c = gh[i];
                if (cum + c >= (uint32_t)K_PRE) break;
                cum += c;
            }
            if (i < top - 16) i = top - 16;
            sub = i;
        }
        meta[MT_T2 + b] = (t1 << 18) | ((uint32_t)sub << 6);
        meta[MT_CNT(b)] = 0;
        meta[MT_KEPT + b] = 0;
    }
}

// 2048 blocks = 256 per batch. Contention-free: LDS stash + ONE padded global
// atomic per block. cand[] slot order is irrelevant (rank pass is order-free).
__global__ __launch_bounds__(256) void k_compact(const float4* __restrict__ probs4,
                                                 const uint32_t* __restrict__ meta,
                                                 uint32_t* cnt_meta, uint64_t* __restrict__ cand) {
    __shared__ uint64_t stash[1024];
    __shared__ uint32_t lcnt, lbase;
    const int b = blockIdx.x >> 8;
    const int s = blockIdx.x & 255;
    const uint32_t T = meta[MT_T2 + b];
    if (threadIdx.x == 0) lcnt = 0;
    __syncthreads();
    const float4* p = probs4 + (size_t)b * (NN / 2) + (size_t)s * 512;
    const uint32_t base_n = (uint32_t)s * 1024;
    for (int i = threadIdx.x; i < 512; i += 256) {
        const float4 v = p[i];
        const uint32_t u1 = fkey(v.y);
        const uint32_t u2 = fkey(v.w);
        if (u1 >= T) {
            const uint32_t pos = atomicAdd(&lcnt, 1u);
            const uint32_t n = base_n + 2u * (uint32_t)i;
            stash[pos] = ((uint64_t)u1 << 32) | (uint32_t)(~n);
        }
        if (u2 >= T) {
            const uint32_t pos = atomicAdd(&lcnt, 1u);
            const uint32_t n = base_n + 2u * (uint32_t)i + 1u;
            stash[pos] = ((uint64_t)u2 << 32) | (uint32_t)(~n);
        }
    }
    __syncthreads();
    if (threadIdx.x == 0) lbase = atomicAdd(&cnt_meta[MT_CNT(b)], lcnt);
    __syncthreads();
    uint64_t* cb = cand + (size_t)b * CAND_CAP;
    const uint32_t n_loc = lcnt, base = lbase;
    for (uint32_t i = threadIdx.x; i < n_loc; i += 256) {
        const uint32_t pos = base + i;
        if (pos < CAND_CAP) cb[pos] = stash[i];
    }
}

// Rank pass A: register-blocked pairwise counting.
// grid = BATCH * 4 i-chunks * 16 j-chunks = 512 blocks, 256 threads.
// Thread owns 8 i-keys in regs; one LDS broadcast read of jk[j] feeds 8
// compares (LDS ops/thread = 512, was 8192). Partial ranks -> partial[b][jc][i].
__global__ __launch_bounds__(256) void k_rank(const uint64_t* __restrict__ cand,
        const uint32_t* __restrict__ meta, uint32_t* __restrict__ partial) {
    const int b  = blockIdx.x >> 6;
    const int ic = (blockIdx.x >> 4) & 3;
    const int jc = blockIdx.x & 15;
    const uint32_t m = min(meta[MT_CNT(b)], (uint32_t)CAND_CAP);
    if ((uint32_t)(jc << 9) >= m) return;   // j-chunk entirely pads
    if ((uint32_t)(ic << 11) >= m) return;  // i-chunk entirely pads
    __shared__ uint64_t jk[512];
    const uint64_t* cb = cand + (size_t)b * CAND_CAP;
    for (int j = threadIdx.x; j < 512; j += 256) jk[j] = cb[(jc << 9) + j];
    __syncthreads();
    const int ibase = (ic << 11) + threadIdx.x * 8;
    uint64_t ki[8];
#pragma unroll
    for (int e = 0; e < 8; ++e) ki[e] = cb[ibase + e];
    uint32_t r[8] = {0, 0, 0, 0, 0, 0, 0, 0};
#pragma unroll 4
    for (int j = 0; j < 512; ++j) {
        const uint64_t kj = jk[j];
#pragma unroll
        for (int e = 0; e < 8; ++e) r[e] += (kj > ki[e]) ? 1u : 0u;
    }
    uint32_t* pr = partial + (((size_t)(b * 16 + jc)) << 13) + ibase;
#pragma unroll
    for (int e = 0; e < 8; ++e) pr[e] = r[e];
}

// Rank pass B: sum partials (active j-chunks only), decode box into rank slot.
// Ranks of valid keys are a permutation of 0..m-1 (keys distinct).
__global__ __launch_bounds__(256) void k_decode(const uint64_t* __restrict__ cand,
        const uint32_t* __restrict__ meta, const uint32_t* __restrict__ partial,
        const float4* __restrict__ bbox, const float4* __restrict__ anch,
        float4* __restrict__ boxes) {
    const int b = blockIdx.x >> 5;
    const int i = ((blockIdx.x & 31) << 8) + threadIdx.x;
    const uint32_t m = min(meta[MT_CNT(b)], (uint32_t)CAND_CAP);
    if ((uint32_t)i >= m) return;
    const int njc = (int)((m + 511) >> 9);
    uint32_t rank = 0;
    for (int jc = 0; jc < njc; ++jc)
        rank += partial[(((size_t)(b * 16 + jc)) << 13) + i];
    if (rank >= (uint32_t)K_PRE) return;
    const uint64_t ki = cand[(size_t)b * CAND_CAP + i];
    const uint32_t n = ~((uint32_t)ki);
    const float4 a = anch[(size_t)b * NN + n];
    const float4 d = bbox[(size_t)b * NN + n];
    float h = a.z - a.x, w = a.w - a.y;
    const float cy0 = a.x + 0.5f * h + d.x * 0.1f * h;
    const float cx0 = a.y + 0.5f * w + d.y * 0.1f * w;
    h = h * expf(d.z * 0.2f);
    w = w * expf(d.w * 0.2f);
    float4 o;
    o.x = fminf(fmaxf(cy0 - 0.5f * h, 0.0f), 1.0f);
    o.y = fminf(fmaxf(cx0 - 0.5f * w, 0.0f), 1.0f);
    o.z = fminf(fmaxf(cy0 + 0.5f * h, 0.0f), 1.0f);
    o.w = fminf(fmaxf(cx0 + 0.5f * w, 0.0f), 1.0f);
    boxes[(size_t)b * K_PRE + rank] = o;
}

__global__ __launch_bounds__(256) void k_matrix(const float4* __restrict__ boxes,
                                                uint32_t* __restrict__ mask) {
    const int blk = blockIdx.x;
    const int b = blk >> 10;
    const int tile = blk & 1023;
    const int ti = tile >> 5, tj = tile & 31;
    __shared__ float4 rb[64], cb[64];
    __shared__ uint32_t wbits[128];
    const float4* bx = boxes + (size_t)b * K_PRE;
    const int t = threadIdx.x;
    if (t < 64) rb[t] = bx[ti * 64 + t];
    else if (t < 128) cb[t - 64] = bx[tj * 64 + (t - 64)];
    if (t < 128) wbits[t] = 0;
    __syncthreads();
    const int r = t >> 2;
    const int cq = t & 3;
    const float4 a = rb[r];
    const float areaA = (a.z - a.x) * (a.w - a.y);
    uint32_t bits = 0;
#pragma unroll
    for (int jj = 0; jj < 16; ++jj) {
        const float4 cc = cb[cq * 16 + jj];
        const float yy1 = fmaxf(a.x, cc.x), xx1 = fmaxf(a.y, cc.y);
        const float yy2 = fminf(a.z, cc.z), xx2 = fminf(a.w, cc.w);
        const float inter = fmaxf(yy2 - yy1, 0.0f) * fmaxf(xx2 - xx1, 0.0f);
        const float areaC = (cc.z - cc.x) * (cc.w - cc.y);
        const float uni = fmaxf(areaA + areaC - inter, 1e-8f);
        if (inter / uni > NMS_THR) bits |= (1u << jj);
    }
    atomicOr(&wbits[r * 2 + (cq >> 1)], bits << ((cq & 1) * 16));
    __syncthreads();
    if (t < 128) {
        const int rr = t >> 1, ww = t & 1;
        mask[((size_t)b * PREFIX + ti * 64 + rr) * 64 + tj * 2 + ww] = wbits[rr * 2 + ww];
    }
}

// Greedy NMS bit-scan over the 2048x2048 suppression matrix.
__global__ __launch_bounds__(256) void k_greedy(const uint32_t* __restrict__ mask,
                                                uint32_t* meta, uint32_t* __restrict__ kept_idx) {
    __shared__ uint32_t lbuf[2][256 * 64];   // 2 x 64 KB
    __shared__ uint32_t skept[8];
    const int b = blockIdx.x;
    const int lane = threadIdx.x & 63;
    const int wave = threadIdx.x >> 6;
    const uint32_t* mrow = mask + (size_t)b * PREFIX * 64;

    {
        const uint4* s4 = (const uint4*)mrow;
        uint4* d4 = (uint4*)lbuf[0];
        for (int idx = threadIdx.x; idx < 4096; idx += 256) d4[idx] = s4[idx];
    }
    __syncthreads();

    uint32_t supp = 0;   // lane l: suppression bits for columns [32l, 32l+32)
    uint32_t kept = 0;

    for (int c = 0; c < PREFIX / 256; ++c) {
        if (wave > 0) {
            if (c + 1 < PREFIX / 256) {
                const uint4* s4 = (const uint4*)(mrow + (size_t)(c + 1) * 256 * 64);
                uint4* d4 = (uint4*)lbuf[(c + 1) & 1];
                for (int idx = threadIdx.x - 64; idx < 4096; idx += 192) d4[idx] = s4[idx];
            }
        } else {
            const uint32_t* L = lbuf[c & 1];
            for (int g = 0; g < 8; ++g) {
                if (kept >= NPROP) break;
                const int grow = c * 256 + g * 32;
                const int w = grow >> 5;
                uint32_t rbuf[32];
#pragma unroll
                for (int q = 0; q < 32; ++q) rbuf[q] = L[(g * 32 + q) * 64 + lane];
                uint32_t sw = __builtin_amdgcn_readlane(supp, w);
#pragma unroll
                for (int q = 0; q < 32; ++q) {
                    if (kept < NPROP && !((sw >> q) & 1u)) {
                        if (lane == 0) kept_idx[(size_t)b * NPROP + kept] = (uint32_t)(grow + q);
                        supp |= rbuf[q];
                        sw |= __builtin_amdgcn_readlane(rbuf[q], w);
                        ++kept;
                    }
                }
            }
            if (lane == 0) skept[c] = kept;
        }
        __syncthreads();
        if (skept[c] >= NPROP) break;
    }
    if (wave == 0 && lane == 0) meta[MT_KEPT + b] = kept;
}

__global__ __launch_bounds__(1024) void k_finish(const float4* __restrict__ boxes,
        uint32_t* meta, uint32_t* kept_idx, float4* __restrict__ out) {
    const int b = blockIdx.x;
    const float4* bx = boxes + (size_t)b * K_PRE;
    __shared__ float4 kb[NPROP];
    __shared__ uint32_t sflag;
    uint32_t kept = meta[MT_KEPT + b];
    if (kept < NPROP) {
        for (uint32_t k = threadIdx.x; k < kept; k += 1024)
            kb[k] = bx[kept_idx[(size_t)b * NPROP + k]];
        __syncthreads();
        for (int i = PREFIX; i < K_PRE && kept < NPROP; ++i) {
            if (threadIdx.x == 0) sflag = 0;
            __syncthreads();
            const float4 c = bx[i];
            const float areaC = (c.z - c.x) * (c.w - c.y);
            bool sup = false;
            for (uint32_t k = threadIdx.x; k < kept; k += 1024) {
                const float4 a = kb[k];
                const float yy1 = fmaxf(c.x, a.x), xx1 = fmaxf(c.y, a.y);
                const float yy2 = fminf(c.z, a.z), xx2 = fminf(c.w, a.w);
                const float inter = fmaxf(yy2 - yy1, 0.0f) * fmaxf(xx2 - xx1, 0.0f);
                const float areaA = (a.z - a.x) * (a.w - a.y);
                const float uni = fmaxf(areaC + areaA - inter, 1e-8f);
                if (inter / uni > NMS_THR) { sup = true; break; }
            }
            if (sup) atomicOr(&sflag, 1u);
            __syncthreads();
            if (sflag == 0) {
                if (threadIdx.x == 0) {
                    kept_idx[(size_t)b * NPROP + kept] = (uint32_t)i;
                    kb[kept] = c;
                }
                ++kept;
            }
            __syncthreads();
        }
        if (threadIdx.x == 0) meta[MT_KEPT + b] = kept;
    }
    __syncthreads();
    for (uint32_t k = threadIdx.x; k < NPROP; k += 1024) {
        float4 v = make_float4(0.f, 0.f, 0.f, 0.f);
        if (k < kept) v = bx[kept_idx[(size_t)b * NPROP + k]];
        out[(size_t)b * NPROP + k] = v;
    }
}

extern "C" void kernel_launch(void* const* d_in, const int* in_sizes, int n_in,
                              void* d_out, int out_size, void* d_ws, size_t ws_size,
                              hipStream_t stream) {
    const float4* probs4 = (const float4*)d_in[0];
    const float4* bbox   = (const float4*)d_in[1];
    const float4* anch   = (const float4*)d_in[2];
    char* ws = (char*)d_ws;
    if (ws_size < (size_t)WS_NEED) return;
    uint32_t* hist1 = (uint32_t*)(ws + HIST1_OFF);
    uint32_t* hist2 = (uint32_t*)(ws + HIST2_OFF);
    uint32_t* meta  = (uint32_t*)(ws + META_OFF);
    uint64_t* cand  = (uint64_t*)(ws + CAND_OFF);
    float4*   boxes = (float4*)(ws + BOXES_OFF);
    uint32_t* mask  = (uint32_t*)(ws + MASK_OFF);
    uint32_t* kidx  = (uint32_t*)(ws + KIDX_OFF);
    uint32_t* partial = (uint32_t*)(ws + MASK_OFF);  // reuse: consumed before k_matrix writes

    k_zero<<<dim3((HZERO + CZERO + 255) / 256), dim3(256), 0, stream>>>(hist1, (uint32_t*)cand);
    k_hist<<<dim3(512), dim3(256), 0, stream>>>(probs4, hist1);
    k_thresh<<<dim3(BATCH), dim3(256), 0, stream>>>(hist1, meta);
    k_hist2<<<dim3(2048), dim3(256), 0, stream>>>(probs4, meta, hist2);
    k_thresh2<<<dim3(BATCH), dim3(256), 0, stream>>>(hist2, meta);
    k_compact<<<dim3(2048), dim3(256), 0, stream>>>(probs4, meta, meta, cand);
    k_rank<<<dim3(BATCH * 64), dim3(256), 0, stream>>>(cand, meta, partial);
    k_decode<<<dim3(BATCH * 32), dim3(256), 0, stream>>>(cand, meta, partial, bbox, anch, boxes);
    k_matrix<<<dim3(BATCH * 1024), dim3(256), 0, stream>>>(boxes, mask);
    k_greedy<<<dim3(BATCH), dim3(256), 0, stream>>>(mask, meta, kidx);
    k_finish<<<dim3(BATCH), dim3(1024), 0, stream>>>(boxes, meta, kidx, (float4*)d_out);
}

// Round 9
// 168.529 us; speedup vs baseline: 1.5209x; 1.2200x over previous
//
#include <hip/hip_runtime.h>
#include <stdint.h>

#define BATCH 8
#define NN 262144
#define K_PRE 6000
#define NPROP 1000
#define NMS_THR 0.7f
#define CAND_CAP 8192
#define PREFIX 2048
#define NB1 16384
#define NB2 4096

// meta u32 indices
#define MT_T2 0        // [0..7]   final threshold (read-only after thresh2)
#define MT_KEPT 16     // [16..23] kept count per batch
#define MT_T1 24       // [24..31] coarse bucket
#define MT_CUM 32      // [32..39] cum count above coarse bucket
#define MT_CNT(b) (64 + 32*(b))   // padded counters, 128B apart

// workspace layout (bytes)
#define HIST1_OFF 0                                   // BATCH*NB1*4 = 524288
#define HIST2_OFF (HIST1_OFF + BATCH*NB1*4)           // + BATCH*NB2*4 = 131072
#define META_OFF  (HIST2_OFF + BATCH*NB2*4)           // 2048 B
#define CAND_OFF  (META_OFF + 2048)
#define BOXES_OFF (CAND_OFF + BATCH*CAND_CAP*8)       // BATCH*K_PRE*16
#define MASK_OFF  (BOXES_OFF + BATCH*K_PRE*16)        // BATCH*PREFIX*64*4 = 4 MB
#define KIDX_OFF  (MASK_OFF + (size_t)BATCH*PREFIX*64*4)
#define WS_NEED   (KIDX_OFF + BATCH*NPROP*4)

// rank partials REUSE the mask region (4MB, written later by k_matrix):
// partial[(b*16 + jc)*8192 + i], BATCH*16*8192*4 = 4 MB exactly.

#define HZERO (BATCH * (NB1 + NB2))                   // u32s of histograms
#define CZERO (BATCH * CAND_CAP * 2)                  // u32s of cand

__device__ __forceinline__ uint32_t fkey(float f) {
    uint32_t b = __float_as_uint(f);
    return b ^ (uint32_t)(((int32_t)b >> 31) | 0x80000000u);
}

// zero the histograms AND the candidate array (pads must be 0 for ranking)
__global__ void k_zero(uint32_t* h, uint32_t* c32) {
    const int i = blockIdx.x * 256 + threadIdx.x;
    if (i < HZERO) h[i] = 0;
    else if (i < HZERO + CZERO) c32[i - HZERO] = 0;
}

// 512 blocks = 64 per batch; each block: 2048 float4 (= 4096 elements).
__global__ __launch_bounds__(256) void k_hist(const float4* __restrict__ probs4,
                                              uint32_t* __restrict__ hist) {
    __shared__ uint32_t h[NB1];
    for (int i = threadIdx.x; i < NB1; i += 256) h[i] = 0;
    __syncthreads();
    const int b = blockIdx.x >> 6;
    const int s = blockIdx.x & 63;
    const float4* p = probs4 + (size_t)b * (NN / 2) + (size_t)s * 2048;
    for (int i = threadIdx.x; i < 2048; i += 256) {
        const float4 v = p[i];
        atomicAdd(&h[fkey(v.y) >> 18], 1u);
        atomicAdd(&h[fkey(v.w) >> 18], 1u);
    }
    __syncthreads();
    uint32_t* gh = hist + (size_t)b * NB1;
    for (int i = threadIdx.x; i < NB1; i += 256)
        if (h[i]) atomicAdd(&gh[i], h[i]);
}

__global__ __launch_bounds__(256) void k_thresh(const uint32_t* __restrict__ hist,
                                                uint32_t* meta) {
    const int b = blockIdx.x;
    const uint32_t* gh = hist + (size_t)b * NB1;
    __shared__ uint32_t part[256];
    const int t = threadIdx.x;
    uint32_t s = 0;
    const int hi = NB1 - 64 * t;
    for (int i = hi - 64; i < hi; ++i) s += gh[i];
    part[t] = s;
    __syncthreads();
    if (t == 0) {
        uint32_t cum = 0;
        int strip = 0;
        for (; strip < 256; ++strip) {
            if (cum + part[strip] >= (uint32_t)K_PRE) break;
            cum += part[strip];
        }
        int t1 = 0;
        if (strip < 256) {
            const int top = NB1 - 64 * strip;
            int i = top - 1;
            for (; i >= top - 64; --i) {
                const uint32_t c = gh[i];
                if (cum + c >= (uint32_t)K_PRE) break;
                cum += c;
            }
            if (i < top - 64) i = top - 64;
            t1 = i;
        }
        meta[MT_T1 + b] = (uint32_t)t1;
        meta[MT_CUM + b] = cum;  // count strictly above bucket t1
    }
}

// 2048 blocks = 256 per batch; ~8k matches per batch spread over 4096 buckets.
__global__ __launch_bounds__(256) void k_hist2(const float4* __restrict__ probs4,
                                               const uint32_t* __restrict__ meta,
                                               uint32_t* __restrict__ hist2) {
    const int b = blockIdx.x >> 8;
    const int s = blockIdx.x & 255;
    const uint32_t t1 = meta[MT_T1 + b];
    const float4* p = probs4 + (size_t)b * (NN / 2) + (size_t)s * 512;
    uint32_t* gh = hist2 + (size_t)b * NB2;
    for (int i = threadIdx.x; i < 512; i += 256) {
        const float4 v = p[i];
        const uint32_t u1 = fkey(v.y);
        const uint32_t u2 = fkey(v.w);
        if ((u1 >> 18) == t1) atomicAdd(&gh[(u1 >> 6) & 0xFFFu], 1u);
        if ((u2 >> 18) == t1) atomicAdd(&gh[(u2 >> 6) & 0xFFFu], 1u);
    }
}

__global__ __launch_bounds__(256) void k_thresh2(const uint32_t* __restrict__ hist2,
                                                 uint32_t* meta) {
    const int b = blockIdx.x;
    const uint32_t* gh = hist2 + (size_t)b * NB2;
    __shared__ uint32_t part[256];
    const int t = threadIdx.x;
    uint32_t s = 0;
    const int hi = NB2 - 16 * t;
    for (int i = hi - 16; i < hi; ++i) s += gh[i];
    part[t] = s;
    __syncthreads();
    if (t == 0) {
        const uint32_t t1 = meta[MT_T1 + b];
        uint32_t cum = meta[MT_CUM + b];
        int strip = 0;
        for (; strip < 256; ++strip) {
            if (cum + part[strip] >= (uint32_t)K_PRE) break;
            cum += part[strip];
        }
        int sub = 0;
        if (strip < 256) {
            const int top = NB2 - 16 * strip;
            int i = top - 1;
            for (; i >= top - 16; --i) {
                const uint32_t c = gh[i];
                if (cum + c >= (uint32_t)K_PRE) break;
                cum += c;
            }
            if (i < top - 16) i = top - 16;
            sub = i;
        }
        meta[MT_T2 + b] = (t1 << 18) | ((uint32_t)sub << 6);
        meta[MT_CNT(b)] = 0;
        meta[MT_KEPT + b] = 0;
    }
}

// 2048 blocks = 256 per batch. Contention-free: LDS stash + ONE padded global
// atomic per block. cand[] slot order is irrelevant (rank pass is order-free).
__global__ __launch_bounds__(256) void k_compact(const float4* __restrict__ probs4,
                                                 const uint32_t* __restrict__ meta,
                                                 uint32_t* cnt_meta, uint64_t* __restrict__ cand) {
    __shared__ uint64_t stash[1024];
    __shared__ uint32_t lcnt, lbase;
    const int b = blockIdx.x >> 8;
    const int s = blockIdx.x & 255;
    const uint32_t T = meta[MT_T2 + b];
    if (threadIdx.x == 0) lcnt = 0;
    __syncthreads();
    const float4* p = probs4 + (size_t)b * (NN / 2) + (size_t)s * 512;
    const uint32_t base_n = (uint32_t)s * 1024;
    for (int i = threadIdx.x; i < 512; i += 256) {
        const float4 v = p[i];
        const uint32_t u1 = fkey(v.y);
        const uint32_t u2 = fkey(v.w);
        if (u1 >= T) {
            const uint32_t pos = atomicAdd(&lcnt, 1u);
            const uint32_t n = base_n + 2u * (uint32_t)i;
            stash[pos] = ((uint64_t)u1 << 32) | (uint32_t)(~n);
        }
        if (u2 >= T) {
            const uint32_t pos = atomicAdd(&lcnt, 1u);
            const uint32_t n = base_n + 2u * (uint32_t)i + 1u;
            stash[pos] = ((uint64_t)u2 << 32) | (uint32_t)(~n);
        }
    }
    __syncthreads();
    if (threadIdx.x == 0) lbase = atomicAdd(&cnt_meta[MT_CNT(b)], lcnt);
    __syncthreads();
    uint64_t* cb = cand + (size_t)b * CAND_CAP;
    const uint32_t n_loc = lcnt, base = lbase;
    for (uint32_t i = threadIdx.x; i < n_loc; i += 256) {
        const uint32_t pos = base + i;
        if (pos < CAND_CAP) cb[pos] = stash[i];
    }
}

// Rank pass A: register-blocked pairwise counting.
__global__ __launch_bounds__(256) void k_rank(const uint64_t* __restrict__ cand,
        const uint32_t* __restrict__ meta, uint32_t* __restrict__ partial) {
    const int b  = blockIdx.x >> 6;
    const int ic = (blockIdx.x >> 4) & 3;
    const int jc = blockIdx.x & 15;
    const uint32_t m = min(meta[MT_CNT(b)], (uint32_t)CAND_CAP);
    if ((uint32_t)(jc << 9) >= m) return;   // j-chunk entirely pads
    if ((uint32_t)(ic << 11) >= m) return;  // i-chunk entirely pads
    __shared__ uint64_t jk[512];
    const uint64_t* cb = cand + (size_t)b * CAND_CAP;
    for (int j = threadIdx.x; j < 512; j += 256) jk[j] = cb[(jc << 9) + j];
    __syncthreads();
    const int ibase = (ic << 11) + threadIdx.x * 8;
    uint64_t ki[8];
#pragma unroll
    for (int e = 0; e < 8; ++e) ki[e] = cb[ibase + e];
    uint32_t r[8] = {0, 0, 0, 0, 0, 0, 0, 0};
#pragma unroll 4
    for (int j = 0; j < 512; ++j) {
        const uint64_t kj = jk[j];
#pragma unroll
        for (int e = 0; e < 8; ++e) r[e] += (kj > ki[e]) ? 1u : 0u;
    }
    uint32_t* pr = partial + (((size_t)(b * 16 + jc)) << 13) + ibase;
#pragma unroll
    for (int e = 0; e < 8; ++e) pr[e] = r[e];
}

// Rank pass B: sum partials (active j-chunks only), decode box into rank slot.
__global__ __launch_bounds__(256) void k_decode(const uint64_t* __restrict__ cand,
        const uint32_t* __restrict__ meta, const uint32_t* __restrict__ partial,
        const float4* __restrict__ bbox, const float4* __restrict__ anch,
        float4* __restrict__ boxes) {
    const int b = blockIdx.x >> 5;
    const int i = ((blockIdx.x & 31) << 8) + threadIdx.x;
    const uint32_t m = min(meta[MT_CNT(b)], (uint32_t)CAND_CAP);
    if ((uint32_t)i >= m) return;
    const int njc = (int)((m + 511) >> 9);
    uint32_t rank = 0;
    for (int jc = 0; jc < njc; ++jc)
        rank += partial[(((size_t)(b * 16 + jc)) << 13) + i];
    if (rank >= (uint32_t)K_PRE) return;
    const uint64_t ki = cand[(size_t)b * CAND_CAP + i];
    const uint32_t n = ~((uint32_t)ki);
    const float4 a = anch[(size_t)b * NN + n];
    const float4 d = bbox[(size_t)b * NN + n];
    float h = a.z - a.x, w = a.w - a.y;
    const float cy0 = a.x + 0.5f * h + d.x * 0.1f * h;
    const float cx0 = a.y + 0.5f * w + d.y * 0.1f * w;
    h = h * expf(d.z * 0.2f);
    w = w * expf(d.w * 0.2f);
    float4 o;
    o.x = fminf(fmaxf(cy0 - 0.5f * h, 0.0f), 1.0f);
    o.y = fminf(fmaxf(cx0 - 0.5f * w, 0.0f), 1.0f);
    o.z = fminf(fmaxf(cy0 + 0.5f * h, 0.0f), 1.0f);
    o.w = fminf(fmaxf(cx0 + 0.5f * w, 0.0f), 1.0f);
    boxes[(size_t)b * K_PRE + rank] = o;
}

__global__ __launch_bounds__(256) void k_matrix(const float4* __restrict__ boxes,
                                                uint32_t* __restrict__ mask) {
    const int blk = blockIdx.x;
    const int b = blk >> 10;
    const int tile = blk & 1023;
    const int ti = tile >> 5, tj = tile & 31;
    __shared__ float4 rb[64], cb[64];
    __shared__ uint32_t wbits[128];
    const float4* bx = boxes + (size_t)b * K_PRE;
    const int t = threadIdx.x;
    if (t < 64) rb[t] = bx[ti * 64 + t];
    else if (t < 128) cb[t - 64] = bx[tj * 64 + (t - 64)];
    if (t < 128) wbits[t] = 0;
    __syncthreads();
    const int r = t >> 2;
    const int cq = t & 3;
    const float4 a = rb[r];
    const float areaA = (a.z - a.x) * (a.w - a.y);
    uint32_t bits = 0;
#pragma unroll
    for (int jj = 0; jj < 16; ++jj) {
        const float4 cc = cb[cq * 16 + jj];
        const float yy1 = fmaxf(a.x, cc.x), xx1 = fmaxf(a.y, cc.y);
        const float yy2 = fminf(a.z, cc.z), xx2 = fminf(a.w, cc.w);
        const float inter = fmaxf(yy2 - yy1, 0.0f) * fmaxf(xx2 - xx1, 0.0f);
        const float areaC = (cc.z - cc.x) * (cc.w - cc.y);
        const float uni = fmaxf(areaA + areaC - inter, 1e-8f);
        if (inter / uni > NMS_THR) bits |= (1u << jj);
    }
    atomicOr(&wbits[r * 2 + (cq >> 1)], bits << ((cq & 1) * 16));
    __syncthreads();
    if (t < 128) {
        const int rr = t >> 1, ww = t & 1;
        mask[((size_t)b * PREFIX + ti * 64 + rr) * 64 + tj * 2 + ww] = wbits[rr * 2 + ww];
    }
}

// Greedy NMS bit-scan: scalar (SALU) within-group closure + vector OR apply.
// Lane g's rbuf holds the 32x32 diagonal block of group g -> readlane to
// uniform regs, serial greedy runs on uniform values (no divergence, 1cy ops).
// Early exit once kept >= NPROP (~half the rows for this data).
__global__ __launch_bounds__(256) void k_greedy(const uint32_t* __restrict__ mask,
                                                uint32_t* meta, uint32_t* __restrict__ kept_idx) {
    __shared__ uint32_t lbuf[2][256 * 64];   // 2 x 64 KB
    __shared__ uint32_t skept[8];
    const int b = blockIdx.x;
    const int lane = threadIdx.x & 63;
    const int wave = threadIdx.x >> 6;
    const uint32_t* mrow = mask + (size_t)b * PREFIX * 64;

    {
        const uint4* s4 = (const uint4*)mrow;
        uint4* d4 = (uint4*)lbuf[0];
        for (int idx = threadIdx.x; idx < 4096; idx += 256) d4[idx] = s4[idx];
    }
    __syncthreads();

    uint32_t supp = 0;       // lane l: suppression bits for columns [32l, 32l+32)
    uint32_t kept = 0;       // wave-0 uniform
    uint32_t tmask_reg = 0;  // lane g holds take-mask of group g

    for (int c = 0; c < PREFIX / 256; ++c) {
        if (wave > 0) {
            if (c + 1 < PREFIX / 256) {
                const uint4* s4 = (const uint4*)(mrow + (size_t)(c + 1) * 256 * 64);
                uint4* d4 = (uint4*)lbuf[(c + 1) & 1];
                for (int idx = threadIdx.x - 64; idx < 4096; idx += 192) d4[idx] = s4[idx];
            }
        } else {
            const uint32_t* L = lbuf[c & 1];
            for (int g8 = 0; g8 < 8; ++g8) {
                const int g = c * 8 + g8;
                uint32_t rbuf[32];
#pragma unroll
                for (int q = 0; q < 32; ++q) rbuf[q] = L[(g8 * 32 + q) * 64 + lane];
                // uniform copy of group-diagonal block + current suppression word
                uint32_t sw = __builtin_amdgcn_readlane(supp, g);
                uint32_t rs[32];
#pragma unroll
                for (int q = 0; q < 32; ++q) rs[q] = __builtin_amdgcn_readlane(rbuf[q], g);
                // scalar greedy closure within the group
                uint32_t take = 0;
#pragma unroll
                for (int q = 0; q < 32; ++q) {
                    if (kept < NPROP && !((sw >> q) & 1u)) {
                        take |= (1u << q);
                        sw |= rs[q];
                        ++kept;
                    }
                }
                // vector-wide suppression apply (no serial chain)
                uint32_t acc = 0;
#pragma unroll
                for (int q = 0; q < 32; ++q)
                    if ((take >> q) & 1u) acc |= rbuf[q];
                supp |= acc;
                // stash take mask at lane g
                if (lane == g) tmask_reg = take;
                if (kept >= NPROP) break;
            }
            if (lane == 0) skept[c] = kept;
        }
        __syncthreads();
        if (skept[c] >= NPROP) break;
    }

    if (wave == 0) {
        // expand take masks -> kept_idx (ascending index == greedy order)
        const uint32_t pc = (uint32_t)__popc(tmask_reg);
        uint32_t pref = pc;
        for (int d = 1; d < 64; d <<= 1) {
            const uint32_t v = __shfl_up(pref, d);
            if (lane >= d) pref += v;
        }
        uint32_t idx = pref - pc;
        uint32_t tm = tmask_reg;
        while (tm) {
            const int q = __ffs(tm) - 1;
            tm &= tm - 1;
            kept_idx[(size_t)b * NPROP + idx] = (uint32_t)(lane * 32 + q);
            ++idx;
        }
        if (lane == 0) meta[MT_KEPT + b] = kept;
    }
}

__global__ __launch_bounds__(1024) void k_finish(const float4* __restrict__ boxes,
        uint32_t* meta, uint32_t* kept_idx, float4* __restrict__ out) {
    const int b = blockIdx.x;
    const float4* bx = boxes + (size_t)b * K_PRE;
    __shared__ float4 kb[NPROP];
    __shared__ uint32_t sflag;
    uint32_t kept = meta[MT_KEPT + b];
    if (kept < NPROP) {
        for (uint32_t k = threadIdx.x; k < kept; k += 1024)
            kb[k] = bx[kept_idx[(size_t)b * NPROP + k]];
        __syncthreads();
        for (int i = PREFIX; i < K_PRE && kept < NPROP; ++i) {
            if (threadIdx.x == 0) sflag = 0;
            __syncthreads();
            const float4 c = bx[i];
            const float areaC = (c.z - c.x) * (c.w - c.y);
            bool sup = false;
            for (uint32_t k = threadIdx.x; k < kept; k += 1024) {
                const float4 a = kb[k];
                const float yy1 = fmaxf(c.x, a.x), xx1 = fmaxf(c.y, a.y);
                const float yy2 = fminf(c.z, a.z), xx2 = fminf(c.w, a.w);
                const float inter = fmaxf(yy2 - yy1, 0.0f) * fmaxf(xx2 - xx1, 0.0f);
                const float areaA = (a.z - a.x) * (a.w - a.y);
                const float uni = fmaxf(areaC + areaA - inter, 1e-8f);
                if (inter / uni > NMS_THR) { sup = true; break; }
            }
            if (sup) atomicOr(&sflag, 1u);
            __syncthreads();
            if (sflag == 0) {
                if (threadIdx.x == 0) {
                    kept_idx[(size_t)b * NPROP + kept] = (uint32_t)i;
                    kb[kept] = c;
                }
                ++kept;
            }
            __syncthreads();
        }
        if (threadIdx.x == 0) meta[MT_KEPT + b] = kept;
    }
    __syncthreads();
    for (uint32_t k = threadIdx.x; k < NPROP; k += 1024) {
        float4 v = make_float4(0.f, 0.f, 0.f, 0.f);
        if (k < kept) v = bx[kept_idx[(size_t)b * NPROP + k]];
        out[(size_t)b * NPROP + k] = v;
    }
}

extern "C" void kernel_launch(void* const* d_in, const int* in_sizes, int n_in,
                              void* d_out, int out_size, void* d_ws, size_t ws_size,
                              hipStream_t stream) {
    const float4* probs4 = (const float4*)d_in[0];
    const float4* bbox   = (const float4*)d_in[1];
    const float4* anch   = (const float4*)d_in[2];
    char* ws = (char*)d_ws;
    if (ws_size < (size_t)WS_NEED) return;
    uint32_t* hist1 = (uint32_t*)(ws + HIST1_OFF);
    uint32_t* hist2 = (uint32_t*)(ws + HIST2_OFF);
    uint32_t* meta  = (uint32_t*)(ws + META_OFF);
    uint64_t* cand  = (uint64_t*)(ws + CAND_OFF);
    float4*   boxes = (float4*)(ws + BOXES_OFF);
    uint32_t* mask  = (uint32_t*)(ws + MASK_OFF);
    uint32_t* kidx  = (uint32_t*)(ws + KIDX_OFF);
    uint32_t* partial = (uint32_t*)(ws + MASK_OFF);  // reuse: consumed before k_matrix writes

    k_zero<<<dim3((HZERO + CZERO + 255) / 256), dim3(256), 0, stream>>>(hist1, (uint32_t*)cand);
    k_hist<<<dim3(512), dim3(256), 0, stream>>>(probs4, hist1);
    k_thresh<<<dim3(BATCH), dim3(256), 0, stream>>>(hist1, meta);
    k_hist2<<<dim3(2048), dim3(256), 0, stream>>>(probs4, meta, hist2);
    k_thresh2<<<dim3(BATCH), dim3(256), 0, stream>>>(hist2, meta);
    k_compact<<<dim3(2048), dim3(256), 0, stream>>>(probs4, meta, meta, cand);
    k_rank<<<dim3(BATCH * 64), dim3(256), 0, stream>>>(cand, meta, partial);
    k_decode<<<dim3(BATCH * 32), dim3(256), 0, stream>>>(cand, meta, partial, bbox, anch, boxes);
    k_matrix<<<dim3(BATCH * 1024), dim3(256), 0, stream>>>(boxes, mask);
    k_greedy<<<dim3(BATCH), dim3(256), 0, stream>>>(mask, meta, kidx);
    k_finish<<<dim3(BATCH), dim3(1024), 0, stream>>>(boxes, meta, kidx, (float4*)d_out);
}

// Round 10
// 142.497 us; speedup vs baseline: 1.7988x; 1.1827x over previous
//
#include <hip/hip_runtime.h>
#include <stdint.h>

#define BATCH 8
#define NN 262144
#define K_PRE 6000
#define NPROP 1000
#define NMS_THR 0.7f
#define CAND_CAP 8192
#define PREFIX 2048
#define NB1 16384
#define NB2 4096

// meta u32 indices
#define MT_T2 0        // [0..7]   final threshold (read-only after thresh2)
#define MT_KEPT 16     // [16..23] kept count per batch
#define MT_T1 24       // [24..31] coarse bucket
#define MT_CUM 32      // [32..39] cum count above coarse bucket
#define MT_CNT(b) (64 + 32*(b))   // padded counters, 128B apart

// workspace layout (bytes)
#define HIST1_OFF 0                                   // BATCH*NB1*4 = 524288
#define HIST2_OFF (HIST1_OFF + BATCH*NB1*4)           // + BATCH*NB2*4 = 131072
#define META_OFF  (HIST2_OFF + BATCH*NB2*4)           // 2048 B
#define CAND_OFF  (META_OFF + 2048)
#define BOXES_OFF (CAND_OFF + BATCH*CAND_CAP*8)       // BATCH*K_PRE*16
#define MASK_OFF  (BOXES_OFF + BATCH*K_PRE*16)        // BATCH*PREFIX*64*4 = 4 MB
#define KIDX_OFF  (MASK_OFF + (size_t)BATCH*PREFIX*64*4)
#define WS_NEED   (KIDX_OFF + BATCH*NPROP*4)

// region reuse (regions dead after their producer phase):
//  - rank partials -> MASK region (consumed before k_matrix writes)
//  - sinfo (suppressor lists, u64[BATCH*PREFIX] = 128KB) -> HIST1 region
//  - cbm (conflicted bitmaps, u32[BATCH*64] = 2KB)       -> HIST2 region

#define HZERO (BATCH * (NB1 + NB2))                   // u32s of histograms
#define CZERO (BATCH * CAND_CAP * 2)                  // u32s of cand

__device__ __forceinline__ uint32_t fkey(float f) {
    uint32_t b = __float_as_uint(f);
    return b ^ (uint32_t)(((int32_t)b >> 31) | 0x80000000u);
}

// zero the histograms AND the candidate array (pads must be 0 for ranking)
__global__ void k_zero(uint32_t* h, uint32_t* c32) {
    const int i = blockIdx.x * 256 + threadIdx.x;
    if (i < HZERO) h[i] = 0;
    else if (i < HZERO + CZERO) c32[i - HZERO] = 0;
}

// 512 blocks = 64 per batch; each block: 2048 float4 (= 4096 elements).
__global__ __launch_bounds__(256) void k_hist(const float4* __restrict__ probs4,
                                              uint32_t* __restrict__ hist) {
    __shared__ uint32_t h[NB1];
    for (int i = threadIdx.x; i < NB1; i += 256) h[i] = 0;
    __syncthreads();
    const int b = blockIdx.x >> 6;
    const int s = blockIdx.x & 63;
    const float4* p = probs4 + (size_t)b * (NN / 2) + (size_t)s * 2048;
    for (int i = threadIdx.x; i < 2048; i += 256) {
        const float4 v = p[i];
        atomicAdd(&h[fkey(v.y) >> 18], 1u);
        atomicAdd(&h[fkey(v.w) >> 18], 1u);
    }
    __syncthreads();
    uint32_t* gh = hist + (size_t)b * NB1;
    for (int i = threadIdx.x; i < NB1; i += 256)
        if (h[i]) atomicAdd(&gh[i], h[i]);
}

__global__ __launch_bounds__(256) void k_thresh(const uint32_t* __restrict__ hist,
                                                uint32_t* meta) {
    const int b = blockIdx.x;
    const uint32_t* gh = hist + (size_t)b * NB1;
    __shared__ uint32_t part[256];
    const int t = threadIdx.x;
    uint32_t s = 0;
    const int hi = NB1 - 64 * t;
    for (int i = hi - 64; i < hi; ++i) s += gh[i];
    part[t] = s;
    __syncthreads();
    if (t == 0) {
        uint32_t cum = 0;
        int strip = 0;
        for (; strip < 256; ++strip) {
            if (cum + part[strip] >= (uint32_t)K_PRE) break;
            cum += part[strip];
        }
        int t1 = 0;
        if (strip < 256) {
            const int top = NB1 - 64 * strip;
            int i = top - 1;
            for (; i >= top - 64; --i) {
                const uint32_t c = gh[i];
                if (cum + c >= (uint32_t)K_PRE) break;
                cum += c;
            }
            if (i < top - 64) i = top - 64;
            t1 = i;
        }
        meta[MT_T1 + b] = (uint32_t)t1;
        meta[MT_CUM + b] = cum;  // count strictly above bucket t1
    }
}

// 2048 blocks = 256 per batch; ~8k matches per batch spread over 4096 buckets.
__global__ __launch_bounds__(256) void k_hist2(const float4* __restrict__ probs4,
                                               const uint32_t* __restrict__ meta,
                                               uint32_t* __restrict__ hist2) {
    const int b = blockIdx.x >> 8;
    const int s = blockIdx.x & 255;
    const uint32_t t1 = meta[MT_T1 + b];
    const float4* p = probs4 + (size_t)b * (NN / 2) + (size_t)s * 512;
    uint32_t* gh = hist2 + (size_t)b * NB2;
    for (int i = threadIdx.x; i < 512; i += 256) {
        const float4 v = p[i];
        const uint32_t u1 = fkey(v.y);
        const uint32_t u2 = fkey(v.w);
        if ((u1 >> 18) == t1) atomicAdd(&gh[(u1 >> 6) & 0xFFFu], 1u);
        if ((u2 >> 18) == t1) atomicAdd(&gh[(u2 >> 6) & 0xFFFu], 1u);
    }
}

__global__ __launch_bounds__(256) void k_thresh2(const uint32_t* __restrict__ hist2,
                                                 uint32_t* meta) {
    const int b = blockIdx.x;
    const uint32_t* gh = hist2 + (size_t)b * NB2;
    __shared__ uint32_t part[256];
    const int t = threadIdx.x;
    uint32_t s = 0;
    const int hi = NB2 - 16 * t;
    for (int i = hi - 16; i < hi; ++i) s += gh[i];
    part[t] = s;
    __syncthreads();
    if (t == 0) {
        const uint32_t t1 = meta[MT_T1 + b];
        uint32_t cum = meta[MT_CUM + b];
        int strip = 0;
        for (; strip < 256; ++strip) {
            if (cum + part[strip] >= (uint32_t)K_PRE) break;
            cum += part[strip];
        }
        int sub = 0;
        if (strip < 256) {
            const int top = NB2 - 16 * strip;
            int i = top - 1;
            for (; i >= top - 16; --i) {
                const uint32_t c = gh[i];
                if (cum + c >= (uint32_t)K_PRE) break;
                cum += c;
            }
            if (i < top - 16) i = top - 16;
            sub = i;
        }
        meta[MT_T2 + b] = (t1 << 18) | ((uint32_t)sub << 6);
        meta[MT_CNT(b)] = 0;
        meta[MT_KEPT + b] = 0;
    }
}

// 2048 blocks = 256 per batch. Contention-free: LDS stash + ONE padded global
// atomic per block. cand[] slot order is irrelevant (rank pass is order-free).
__global__ __launch_bounds__(256) void k_compact(const float4* __restrict__ probs4,
                                                 const uint32_t* __restrict__ meta,
                                                 uint32_t* cnt_meta, uint64_t* __restrict__ cand) {
    __shared__ uint64_t stash[1024];
    __shared__ uint32_t lcnt, lbase;
    const int b = blockIdx.x >> 8;
    const int s = blockIdx.x & 255;
    const uint32_t T = meta[MT_T2 + b];
    if (threadIdx.x == 0) lcnt = 0;
    __syncthreads();
    const float4* p = probs4 + (size_t)b * (NN / 2) + (size_t)s * 512;
    const uint32_t base_n = (uint32_t)s * 1024;
    for (int i = threadIdx.x; i < 512; i += 256) {
        const float4 v = p[i];
        const uint32_t u1 = fkey(v.y);
        const uint32_t u2 = fkey(v.w);
        if (u1 >= T) {
            const uint32_t pos = atomicAdd(&lcnt, 1u);
            const uint32_t n = base_n + 2u * (uint32_t)i;
            stash[pos] = ((uint64_t)u1 << 32) | (uint32_t)(~n);
        }
        if (u2 >= T) {
            const uint32_t pos = atomicAdd(&lcnt, 1u);
            const uint32_t n = base_n + 2u * (uint32_t)i + 1u;
            stash[pos] = ((uint64_t)u2 << 32) | (uint32_t)(~n);
        }
    }
    __syncthreads();
    if (threadIdx.x == 0) lbase = atomicAdd(&cnt_meta[MT_CNT(b)], lcnt);
    __syncthreads();
    uint64_t* cb = cand + (size_t)b * CAND_CAP;
    const uint32_t n_loc = lcnt, base = lbase;
    for (uint32_t i = threadIdx.x; i < n_loc; i += 256) {
        const uint32_t pos = base + i;
        if (pos < CAND_CAP) cb[pos] = stash[i];
    }
}

// Rank pass A: register-blocked pairwise counting.
__global__ __launch_bounds__(256) void k_rank(const uint64_t* __restrict__ cand,
        const uint32_t* __restrict__ meta, uint32_t* __restrict__ partial) {
    const int b  = blockIdx.x >> 6;
    const int ic = (blockIdx.x >> 4) & 3;
    const int jc = blockIdx.x & 15;
    const uint32_t m = min(meta[MT_CNT(b)], (uint32_t)CAND_CAP);
    if ((uint32_t)(jc << 9) >= m) return;   // j-chunk entirely pads
    if ((uint32_t)(ic << 11) >= m) return;  // i-chunk entirely pads
    __shared__ uint64_t jk[512];
    const uint64_t* cb = cand + (size_t)b * CAND_CAP;
    for (int j = threadIdx.x; j < 512; j += 256) jk[j] = cb[(jc << 9) + j];
    __syncthreads();
    const int ibase = (ic << 11) + threadIdx.x * 8;
    uint64_t ki[8];
#pragma unroll
    for (int e = 0; e < 8; ++e) ki[e] = cb[ibase + e];
    uint32_t r[8] = {0, 0, 0, 0, 0, 0, 0, 0};
#pragma unroll 4
    for (int j = 0; j < 512; ++j) {
        const uint64_t kj = jk[j];
#pragma unroll
        for (int e = 0; e < 8; ++e) r[e] += (kj > ki[e]) ? 1u : 0u;
    }
    uint32_t* pr = partial + (((size_t)(b * 16 + jc)) << 13) + ibase;
#pragma unroll
    for (int e = 0; e < 8; ++e) pr[e] = r[e];
}

// Rank pass B: sum partials (active j-chunks only), decode box into rank slot.
__global__ __launch_bounds__(256) void k_decode(const uint64_t* __restrict__ cand,
        const uint32_t* __restrict__ meta, const uint32_t* __restrict__ partial,
        const float4* __restrict__ bbox, const float4* __restrict__ anch,
        float4* __restrict__ boxes) {
    const int b = blockIdx.x >> 5;
    const int i = ((blockIdx.x & 31) << 8) + threadIdx.x;
    const uint32_t m = min(meta[MT_CNT(b)], (uint32_t)CAND_CAP);
    if ((uint32_t)i >= m) return;
    const int njc = (int)((m + 511) >> 9);
    uint32_t rank = 0;
    for (int jc = 0; jc < njc; ++jc)
        rank += partial[(((size_t)(b * 16 + jc)) << 13) + i];
    if (rank >= (uint32_t)K_PRE) return;
    const uint64_t ki = cand[(size_t)b * CAND_CAP + i];
    const uint32_t n = ~((uint32_t)ki);
    const float4 a = anch[(size_t)b * NN + n];
    const float4 d = bbox[(size_t)b * NN + n];
    float h = a.z - a.x, w = a.w - a.y;
    const float cy0 = a.x + 0.5f * h + d.x * 0.1f * h;
    const float cx0 = a.y + 0.5f * w + d.y * 0.1f * w;
    h = h * expf(d.z * 0.2f);
    w = w * expf(d.w * 0.2f);
    float4 o;
    o.x = fminf(fmaxf(cy0 - 0.5f * h, 0.0f), 1.0f);
    o.y = fminf(fmaxf(cx0 - 0.5f * w, 0.0f), 1.0f);
    o.z = fminf(fmaxf(cy0 + 0.5f * h, 0.0f), 1.0f);
    o.w = fminf(fmaxf(cx0 + 0.5f * w, 0.0f), 1.0f);
    boxes[(size_t)b * K_PRE + rank] = o;
}

__global__ __launch_bounds__(256) void k_matrix(const float4* __restrict__ boxes,
                                                uint32_t* __restrict__ mask) {
    const int blk = blockIdx.x;
    const int b = blk >> 10;
    const int tile = blk & 1023;
    const int ti = tile >> 5, tj = tile & 31;
    __shared__ float4 rb[64], cb[64];
    __shared__ uint32_t wbits[128];
    const float4* bx = boxes + (size_t)b * K_PRE;
    const int t = threadIdx.x;
    if (t < 64) rb[t] = bx[ti * 64 + t];
    else if (t < 128) cb[t - 64] = bx[tj * 64 + (t - 64)];
    if (t < 128) wbits[t] = 0;
    __syncthreads();
    const int r = t >> 2;
    const int cq = t & 3;
    const float4 a = rb[r];
    const float areaA = (a.z - a.x) * (a.w - a.y);
    uint32_t bits = 0;
#pragma unroll
    for (int jj = 0; jj < 16; ++jj) {
        const float4 cc = cb[cq * 16 + jj];
        const float yy1 = fmaxf(a.x, cc.x), xx1 = fmaxf(a.y, cc.y);
        const float yy2 = fminf(a.z, cc.z), xx2 = fminf(a.w, cc.w);
        const float inter = fmaxf(yy2 - yy1, 0.0f) * fmaxf(xx2 - xx1, 0.0f);
        const float areaC = (cc.z - cc.x) * (cc.w - cc.y);
        const float uni = fmaxf(areaA + areaC - inter, 1e-8f);
        if (inter / uni > NMS_THR) bits |= (1u << jj);
    }
    atomicOr(&wbits[r * 2 + (cq >> 1)], bits << ((cq & 1) * 16));
    __syncthreads();
    if (t < 128) {
        const int rr = t >> 1, ww = t & 1;
        mask[((size_t)b * PREFIX + ti * 64 + rr) * 64 + tj * 2 + ww] = wbits[rr * 2 + ww];
    }
}

// Conflict extraction: mask is symmetric, so "row i has an earlier suppressor"
// == "row i has a set bit below its diagonal". 1 thread per row; pack up to 5
// suppressor indices (12b each) + count into a u64. Conflicted bitmap written
// per-wave via ballot (disjoint words -> no atomics, no zeroing).
__global__ __launch_bounds__(256) void k_conflict(const uint32_t* __restrict__ mask,
        uint64_t* __restrict__ sinfo, uint32_t* __restrict__ cbm) {
    const int b = blockIdx.x >> 3;
    const int s = blockIdx.x & 7;
    const int i = (s << 8) + threadIdx.x;
    const uint4* row4 = (const uint4*)(mask + ((size_t)b * PREFIX + i) * 64);
    const int iw = i >> 5;
    const uint32_t tailmask = ((uint32_t)1 << (i & 31)) - 1u;
    uint32_t cnt = 0;
    uint64_t packed = 0;
    for (int c = 0; c <= (iw >> 2); ++c) {
        const uint4 q = row4[c];
        uint32_t ws[4] = {q.x, q.y, q.z, q.w};
#pragma unroll
        for (int k = 0; k < 4; ++k) {
            const int w = c * 4 + k;
            uint32_t bits = ws[k];
            if (w > iw) bits = 0;
            else if (w == iw) bits &= tailmask;
            while (bits) {
                const int bp = __ffs(bits) - 1;
                bits &= bits - 1;
                if (cnt < 5) packed |= (uint64_t)(uint32_t)(w * 32 + bp) << (12 * cnt);
                ++cnt;
            }
        }
    }
    packed |= (uint64_t)(cnt <= 5 ? cnt : 6) << 60;   // 6 = heavy (rescan row)
    sinfo[(size_t)b * PREFIX + i] = packed;
    const unsigned long long bm = __ballot(cnt != 0);
    const int wv = threadIdx.x >> 6;
    const int lid = threadIdx.x & 63;
    if (lid == 0) cbm[(size_t)b * 64 + (s << 3) + wv * 2] = (uint32_t)bm;
    else if (lid == 1) cbm[(size_t)b * 64 + (s << 3) + wv * 2 + 1] = (uint32_t)(bm >> 32);
}

// Greedy resolution: taken-bitmap in lane registers (lane l = word l).
// Non-conflicted rows are unconditionally taken; only conflicted rows (~3%)
// are resolved serially in ascending order using readlane on the taken words.
// Emit first min(1000, total) taken rows (ascending == greedy order).
__global__ __launch_bounds__(64) void k_greedy(const uint32_t* __restrict__ mask,
        const uint64_t* __restrict__ sinfo, const uint32_t* __restrict__ cbm,
        uint32_t* meta, uint32_t* __restrict__ kept_idx) {
    __shared__ uint32_t conf_rows[PREFIX];
    __shared__ uint32_t ncf_s;
    const int b = blockIdx.x;
    const int lane = threadIdx.x;
    const uint32_t cw = cbm[(size_t)b * 64 + lane];
    uint32_t taken = 0xFFFFFFFFu;

    // compact conflicted row indices (ascending)
    const uint32_t pc = (uint32_t)__popc(cw);
    uint32_t pref = pc;
    for (int d = 1; d < 64; d <<= 1) {
        const uint32_t v = __shfl_up(pref, d);
        if (lane >= d) pref += v;
    }
    const uint32_t ncf = __shfl(pref, 63);
    uint32_t idx = pref - pc;
    uint32_t tm = cw;
    while (tm) {
        const int q = __ffs(tm) - 1;
        tm &= tm - 1;
        conf_rows[idx] = (uint32_t)(lane * 32 + q);
        ++idx;
    }
    if (lane == 0) ncf_s = ncf;
    __syncthreads();

    // prefetch first 256 (i, info) pairs into registers
    uint32_t r_i[4], r_lo[4], r_hi[4];
#pragma unroll
    for (int r = 0; r < 4; ++r) {
        const uint32_t k = (uint32_t)(r * 64 + lane);
        const uint32_t ri = (k < ncf) ? conf_rows[k] : 0;
        const uint64_t nf = (k < ncf) ? sinfo[(size_t)b * PREFIX + ri] : 0ull;
        r_i[r] = ri;
        r_lo[r] = (uint32_t)nf;
        r_hi[r] = (uint32_t)(nf >> 32);
    }

    const uint32_t* mbase = mask + (size_t)b * PREFIX * 64;

    // serial resolve (wave-uniform), prefetched segments
#pragma unroll
    for (int seg = 0; seg < 4; ++seg) {
        const uint32_t segbase = (uint32_t)(seg * 64);
        if (segbase < ncf) {
            const uint32_t segcnt = min(64u, ncf - segbase);
            for (uint32_t k2 = 0; k2 < segcnt; ++k2) {
                const uint32_t i  = __builtin_amdgcn_readlane(r_i[seg], (int)k2);
                const uint32_t lo = __builtin_amdgcn_readlane(r_lo[seg], (int)k2);
                const uint32_t hi = __builtin_amdgcn_readlane(r_hi[seg], (int)k2);
                const uint32_t cnt = hi >> 28;
                bool dropped = false;
                if (cnt == 6) {   // heavy: rescan row lower-triangle vs taken
                    const uint32_t* row = mbase + (size_t)i * 64;
                    const int iw = i >> 5;
                    for (int w = 0; w <= iw; ++w) {
                        uint32_t bits = row[w];
                        if (w == iw) bits &= (((uint32_t)1 << (i & 31)) - 1u);
                        const uint32_t tk = __builtin_amdgcn_readlane(taken, w);
                        if (bits & tk) { dropped = true; break; }
                    }
                } else {
                    uint64_t p = ((uint64_t)hi << 32) | lo;
                    for (uint32_t c = 0; c < cnt; ++c) {
                        const uint32_t j = (uint32_t)(p & 0xFFFu);
                        p >>= 12;
                        const uint32_t tk = __builtin_amdgcn_readlane(taken, (int)(j >> 5));
                        if ((tk >> (j & 31)) & 1u) dropped = true;
                    }
                }
                if (dropped) {
                    const int w = (int)(i >> 5);
                    if (lane == w) taken &= ~((uint32_t)1 << (i & 31));
                }
            }
        }
    }
    // tail (>256 conflicted rows): uniform slow path, correctness fallback
    for (uint32_t k = 256; k < ncf; ++k) {
        const uint32_t i = conf_rows[k];
        const uint64_t nf = sinfo[(size_t)b * PREFIX + i];
        const uint32_t cnt = (uint32_t)(nf >> 60);
        bool dropped = false;
        if (cnt == 6) {
            const uint32_t* row = mbase + (size_t)i * 64;
            const int iw = i >> 5;
            for (int w = 0; w <= iw; ++w) {
                uint32_t bits = row[w];
                if (w == iw) bits &= (((uint32_t)1 << (i & 31)) - 1u);
                const uint32_t tk = __builtin_amdgcn_readlane(taken, w);
                if (bits & tk) { dropped = true; break; }
            }
        } else {
            uint64_t p = nf;
            for (uint32_t c = 0; c < cnt; ++c) {
                const uint32_t j = (uint32_t)(p & 0xFFFu);
                p >>= 12;
                const uint32_t tk = __builtin_amdgcn_readlane(taken, (int)(j >> 5));
                if ((tk >> (j & 31)) & 1u) dropped = true;
            }
        }
        if (dropped) {
            const int w = (int)(i >> 5);
            if (lane == w) taken &= ~((uint32_t)1 << (i & 31));
        }
    }

    // emit: ascending taken rows, rank < NPROP
    const uint32_t tpc = (uint32_t)__popc(taken);
    uint32_t tpref = tpc;
    for (int d = 1; d < 64; d <<= 1) {
        const uint32_t v = __shfl_up(tpref, d);
        if (lane >= d) tpref += v;
    }
    const uint32_t total = __shfl(tpref, 63);
    uint32_t rank = tpref - tpc;
    uint32_t w = taken;
    while (w) {
        const int q = __ffs(w) - 1;
        w &= w - 1;
        if (rank < (uint32_t)NPROP)
            kept_idx[(size_t)b * NPROP + rank] = (uint32_t)(lane * 32 + q);
        ++rank;
    }
    if (lane == 0) meta[MT_KEPT + b] = min(total, (uint32_t)NPROP);
}

__global__ __launch_bounds__(1024) void k_finish(const float4* __restrict__ boxes,
        uint32_t* meta, uint32_t* kept_idx, float4* __restrict__ out) {
    const int b = blockIdx.x;
    const float4* bx = boxes + (size_t)b * K_PRE;
    __shared__ float4 kb[NPROP];
    __shared__ uint32_t sflag;
    uint32_t kept = meta[MT_KEPT + b];
    if (kept < NPROP) {
        for (uint32_t k = threadIdx.x; k < kept; k += 1024)
            kb[k] = bx[kept_idx[(size_t)b * NPROP + k]];
        __syncthreads();
        for (int i = PREFIX; i < K_PRE && kept < NPROP; ++i) {
            if (threadIdx.x == 0) sflag = 0;
            __syncthreads();
            const float4 c = bx[i];
            const float areaC = (c.z - c.x) * (c.w - c.y);
            bool sup = false;
            for (uint32_t k = threadIdx.x; k < kept; k += 1024) {
                const float4 a = kb[k];
                const float yy1 = fmaxf(c.x, a.x), xx1 = fmaxf(c.y, a.y);
                const float yy2 = fminf(c.z, a.z), xx2 = fminf(c.w, a.w);
                const float inter = fmaxf(yy2 - yy1, 0.0f) * fmaxf(xx2 - xx1, 0.0f);
                const float areaA = (a.z - a.x) * (a.w - a.y);
                const float uni = fmaxf(areaC + areaA - inter, 1e-8f);
                if (inter / uni > NMS_THR) { sup = true; break; }
            }
            if (sup) atomicOr(&sflag, 1u);
            __syncthreads();
            if (sflag == 0) {
                if (threadIdx.x == 0) {
                    kept_idx[(size_t)b * NPROP + kept] = (uint32_t)i;
                    kb[kept] = c;
                }
                ++kept;
            }
            __syncthreads();
        }
        if (threadIdx.x == 0) meta[MT_KEPT + b] = kept;
    }
    __syncthreads();
    for (uint32_t k = threadIdx.x; k < NPROP; k += 1024) {
        float4 v = make_float4(0.f, 0.f, 0.f, 0.f);
        if (k < kept) v = bx[kept_idx[(size_t)b * NPROP + k]];
        out[(size_t)b * NPROP + k] = v;
    }
}

extern "C" void kernel_launch(void* const* d_in, const int* in_sizes, int n_in,
                              void* d_out, int out_size, void* d_ws, size_t ws_size,
                              hipStream_t stream) {
    const float4* probs4 = (const float4*)d_in[0];
    const float4* bbox   = (const float4*)d_in[1];
    const float4* anch   = (const float4*)d_in[2];
    char* ws = (char*)d_ws;
    if (ws_size < (size_t)WS_NEED) return;
    uint32_t* hist1 = (uint32_t*)(ws + HIST1_OFF);
    uint32_t* hist2 = (uint32_t*)(ws + HIST2_OFF);
    uint32_t* meta  = (uint32_t*)(ws + META_OFF);
    uint64_t* cand  = (uint64_t*)(ws + CAND_OFF);
    float4*   boxes = (float4*)(ws + BOXES_OFF);
    uint32_t* mask  = (uint32_t*)(ws + MASK_OFF);
    uint32_t* kidx  = (uint32_t*)(ws + KIDX_OFF);
    uint32_t* partial = (uint32_t*)(ws + MASK_OFF);  // reuse: consumed before k_matrix writes
    uint64_t* sinfo = (uint64_t*)(ws + HIST1_OFF);   // reuse: hist1 dead after k_thresh
    uint32_t* cbm   = (uint32_t*)(ws + HIST2_OFF);   // reuse: hist2 dead after k_thresh2

    k_zero<<<dim3((HZERO + CZERO + 255) / 256), dim3(256), 0, stream>>>(hist1, (uint32_t*)cand);
    k_hist<<<dim3(512), dim3(256), 0, stream>>>(probs4, hist1);
    k_thresh<<<dim3(BATCH), dim3(256), 0, stream>>>(hist1, meta);
    k_hist2<<<dim3(2048), dim3(256), 0, stream>>>(probs4, meta, hist2);
    k_thresh2<<<dim3(BATCH), dim3(256), 0, stream>>>(hist2, meta);
    k_compact<<<dim3(2048), dim3(256), 0, stream>>>(probs4, meta, meta, cand);
    k_rank<<<dim3(BATCH * 64), dim3(256), 0, stream>>>(cand, meta, partial);
    k_decode<<<dim3(BATCH * 32), dim3(256), 0, stream>>>(cand, meta, partial, bbox, anch, boxes);
    k_matrix<<<dim3(BATCH * 1024), dim3(256), 0, stream>>>(boxes, mask);
    k_conflict<<<dim3(BATCH * 8), dim3(256), 0, stream>>>(mask, sinfo, cbm);
    k_greedy<<<dim3(BATCH), dim3(64), 0, stream>>>(mask, sinfo, cbm, meta, kidx);
    k_finish<<<dim3(BATCH), dim3(1024), 0, stream>>>(boxes, meta, kidx, (float4*)d_out);
}

// Round 11
// 137.746 us; speedup vs baseline: 1.8608x; 1.0345x over previous
//
#include <hip/hip_runtime.h>
#include <stdint.h>

#define BATCH 8
#define NN 262144
#define K_PRE 6000
#define NPROP 1000
#define NMS_THR 0.7f
#define CAND_CAP 8192
#define PREFIX 2048
#define NB1 16384
#define NB2 4096

// meta u32 indices
#define MT_T2 0        // [0..7]   final threshold (read-only after thresh2)
#define MT_KEPT 16     // [16..23] kept count per batch
#define MT_T1 24       // [24..31] coarse bucket
#define MT_CUM 32      // [32..39] cum count above coarse bucket
#define MT_CNT(b) (64 + 32*(b))   // padded counters, 128B apart

// workspace layout (bytes)
#define HIST1_OFF 0                                   // BATCH*NB1*4 = 524288
#define HIST2_OFF (HIST1_OFF + BATCH*NB1*4)           // + BATCH*NB2*4 = 131072
#define META_OFF  (HIST2_OFF + BATCH*NB2*4)           // 2048 B
#define CAND_OFF  (META_OFF + 2048)
#define BOXES_OFF (CAND_OFF + BATCH*CAND_CAP*8)       // BATCH*K_PRE*16
#define MASK_OFF  (BOXES_OFF + BATCH*K_PRE*16)        // BATCH*PREFIX*64*4 = 4 MB
#define KIDX_OFF  (MASK_OFF + (size_t)BATCH*PREFIX*64*4)
#define WS_NEED   (KIDX_OFF + BATCH*NPROP*4)

// region reuse (regions dead after their producer phase):
//  - rank partials -> MASK region (consumed before k_matrix writes)
//  - sinfo (suppressor lists, u64[BATCH*PREFIX] = 128KB) -> HIST1 region
//  - cbm (conflicted bitmaps, u32[BATCH*64] = 2KB)       -> HIST2 region

#define HZERO (BATCH * (NB1 + NB2))                   // u32s of histograms
#define CZERO (BATCH * CAND_CAP * 2)                  // u32s of cand

__device__ __forceinline__ uint32_t fkey(float f) {
    uint32_t b = __float_as_uint(f);
    return b ^ (uint32_t)(((int32_t)b >> 31) | 0x80000000u);
}

// zero the histograms AND the candidate array (pads must be 0 for ranking)
__global__ void k_zero(uint32_t* h, uint32_t* c32) {
    const int i = blockIdx.x * 256 + threadIdx.x;
    if (i < HZERO) h[i] = 0;
    else if (i < HZERO + CZERO) c32[i - HZERO] = 0;
}

// 512 blocks = 64 per batch; each block: 2048 float4 (= 4096 elements).
__global__ __launch_bounds__(256) void k_hist(const float4* __restrict__ probs4,
                                              uint32_t* __restrict__ hist) {
    __shared__ uint32_t h[NB1];
    for (int i = threadIdx.x; i < NB1; i += 256) h[i] = 0;
    __syncthreads();
    const int b = blockIdx.x >> 6;
    const int s = blockIdx.x & 63;
    const float4* p = probs4 + (size_t)b * (NN / 2) + (size_t)s * 2048;
    for (int i = threadIdx.x; i < 2048; i += 256) {
        const float4 v = p[i];
        atomicAdd(&h[fkey(v.y) >> 18], 1u);
        atomicAdd(&h[fkey(v.w) >> 18], 1u);
    }
    __syncthreads();
    uint32_t* gh = hist + (size_t)b * NB1;
    for (int i = threadIdx.x; i < NB1; i += 256)
        if (h[i]) atomicAdd(&gh[i], h[i]);
}

__global__ __launch_bounds__(256) void k_thresh(const uint32_t* __restrict__ hist,
                                                uint32_t* meta) {
    const int b = blockIdx.x;
    const uint32_t* gh = hist + (size_t)b * NB1;
    __shared__ uint32_t part[256];
    const int t = threadIdx.x;
    uint32_t s = 0;
    const int hi = NB1 - 64 * t;
    for (int i = hi - 64; i < hi; ++i) s += gh[i];
    part[t] = s;
    __syncthreads();
    if (t == 0) {
        uint32_t cum = 0;
        int strip = 0;
        for (; strip < 256; ++strip) {
            if (cum + part[strip] >= (uint32_t)K_PRE) break;
            cum += part[strip];
        }
        int t1 = 0;
        if (strip < 256) {
            const int top = NB1 - 64 * strip;
            int i = top - 1;
            for (; i >= top - 64; --i) {
                const uint32_t c = gh[i];
                if (cum + c >= (uint32_t)K_PRE) break;
                cum += c;
            }
            if (i < top - 64) i = top - 64;
            t1 = i;
        }
        meta[MT_T1 + b] = (uint32_t)t1;
        meta[MT_CUM + b] = cum;  // count strictly above bucket t1
    }
}

// 2048 blocks = 256 per batch; ~8k matches per batch spread over 4096 buckets.
__global__ __launch_bounds__(256) void k_hist2(const float4* __restrict__ probs4,
                                               const uint32_t* __restrict__ meta,
                                               uint32_t* __restrict__ hist2) {
    const int b = blockIdx.x >> 8;
    const int s = blockIdx.x & 255;
    const uint32_t t1 = meta[MT_T1 + b];
    const float4* p = probs4 + (size_t)b * (NN / 2) + (size_t)s * 512;
    uint32_t* gh = hist2 + (size_t)b * NB2;
    for (int i = threadIdx.x; i < 512; i += 256) {
        const float4 v = p[i];
        const uint32_t u1 = fkey(v.y);
        const uint32_t u2 = fkey(v.w);
        if ((u1 >> 18) == t1) atomicAdd(&gh[(u1 >> 6) & 0xFFFu], 1u);
        if ((u2 >> 18) == t1) atomicAdd(&gh[(u2 >> 6) & 0xFFFu], 1u);
    }
}

__global__ __launch_bounds__(256) void k_thresh2(const uint32_t* __restrict__ hist2,
                                                 uint32_t* meta) {
    const int b = blockIdx.x;
    const uint32_t* gh = hist2 + (size_t)b * NB2;
    __shared__ uint32_t part[256];
    const int t = threadIdx.x;
    uint32_t s = 0;
    const int hi = NB2 - 16 * t;
    for (int i = hi - 16; i < hi; ++i) s += gh[i];
    part[t] = s;
    __syncthreads();
    if (t == 0) {
        const uint32_t t1 = meta[MT_T1 + b];
        uint32_t cum = meta[MT_CUM + b];
        int strip = 0;
        for (; strip < 256; ++strip) {
            if (cum + part[strip] >= (uint32_t)K_PRE) break;
            cum += part[strip];
        }
        int sub = 0;
        if (strip < 256) {
            const int top = NB2 - 16 * strip;
            int i = top - 1;
            for (; i >= top - 16; --i) {
                const uint32_t c = gh[i];
                if (cum + c >= (uint32_t)K_PRE) break;
                cum += c;
            }
            if (i < top - 16) i = top - 16;
            sub = i;
        }
        meta[MT_T2 + b] = (t1 << 18) | ((uint32_t)sub << 6);
        meta[MT_CNT(b)] = 0;
        meta[MT_KEPT + b] = 0;
    }
}

// 2048 blocks = 256 per batch. Contention-free: LDS stash + ONE padded global
// atomic per block. cand[] slot order is irrelevant (rank pass is order-free).
__global__ __launch_bounds__(256) void k_compact(const float4* __restrict__ probs4,
                                                 const uint32_t* __restrict__ meta,
                                                 uint32_t* cnt_meta, uint64_t* __restrict__ cand) {
    __shared__ uint64_t stash[1024];
    __shared__ uint32_t lcnt, lbase;
    const int b = blockIdx.x >> 8;
    const int s = blockIdx.x & 255;
    const uint32_t T = meta[MT_T2 + b];
    if (threadIdx.x == 0) lcnt = 0;
    __syncthreads();
    const float4* p = probs4 + (size_t)b * (NN / 2) + (size_t)s * 512;
    const uint32_t base_n = (uint32_t)s * 1024;
    for (int i = threadIdx.x; i < 512; i += 256) {
        const float4 v = p[i];
        const uint32_t u1 = fkey(v.y);
        const uint32_t u2 = fkey(v.w);
        if (u1 >= T) {
            const uint32_t pos = atomicAdd(&lcnt, 1u);
            const uint32_t n = base_n + 2u * (uint32_t)i;
            stash[pos] = ((uint64_t)u1 << 32) | (uint32_t)(~n);
        }
        if (u2 >= T) {
            const uint32_t pos = atomicAdd(&lcnt, 1u);
            const uint32_t n = base_n + 2u * (uint32_t)i + 1u;
            stash[pos] = ((uint64_t)u2 << 32) | (uint32_t)(~n);
        }
    }
    __syncthreads();
    if (threadIdx.x == 0) lbase = atomicAdd(&cnt_meta[MT_CNT(b)], lcnt);
    __syncthreads();
    uint64_t* cb = cand + (size_t)b * CAND_CAP;
    const uint32_t n_loc = lcnt, base = lbase;
    for (uint32_t i = threadIdx.x; i < n_loc; i += 256) {
        const uint32_t pos = base + i;
        if (pos < CAND_CAP) cb[pos] = stash[i];
    }
}

// Rank pass A: register-blocked pairwise counting.
// grid = BATCH * 8 i-chunks(1024) * 16 j-chunks(512) = 1024 blocks -> ~576
// active (~2.25/CU, 9 waves/CU). Thread owns 4 i-keys; j-keys read as uint4
// (2 keys per ds_read_b128). Exact u64 compares -> bit-exact ranks.
__global__ __launch_bounds__(256) void k_rank(const uint64_t* __restrict__ cand,
        const uint32_t* __restrict__ meta, uint32_t* __restrict__ partial) {
    const int b  = blockIdx.x >> 7;
    const int ic = (blockIdx.x >> 4) & 7;
    const int jc = blockIdx.x & 15;
    const uint32_t m = min(meta[MT_CNT(b)], (uint32_t)CAND_CAP);
    if ((uint32_t)(jc << 9) >= m) return;   // j-chunk entirely pads
    if ((uint32_t)(ic << 10) >= m) return;  // i-chunk entirely pads
    __shared__ __align__(16) uint64_t jk[512];
    const uint64_t* cb = cand + (size_t)b * CAND_CAP;
    for (int j = threadIdx.x; j < 512; j += 256) jk[j] = cb[(jc << 9) + j];
    __syncthreads();
    const int ibase = (ic << 10) + threadIdx.x * 4;
    uint64_t ki[4];
#pragma unroll
    for (int e = 0; e < 4; ++e) ki[e] = cb[ibase + e];
    uint32_t r[4] = {0, 0, 0, 0};
    const uint4* jk4 = (const uint4*)jk;
#pragma unroll 4
    for (int j4 = 0; j4 < 256; ++j4) {
        const uint4 q = jk4[j4];
        const uint64_t kj0 = ((uint64_t)q.y << 32) | q.x;
        const uint64_t kj1 = ((uint64_t)q.w << 32) | q.z;
#pragma unroll
        for (int e = 0; e < 4; ++e) {
            r[e] += (kj0 > ki[e]) ? 1u : 0u;
            r[e] += (kj1 > ki[e]) ? 1u : 0u;
        }
    }
    uint32_t* pr = partial + (((size_t)(b * 16 + jc)) << 13) + ibase;
#pragma unroll
    for (int e = 0; e < 4; ++e) pr[e] = r[e];
}

// Rank pass B: sum partials (active j-chunks only), decode box into rank slot.
__global__ __launch_bounds__(256) void k_decode(const uint64_t* __restrict__ cand,
        const uint32_t* __restrict__ meta, const uint32_t* __restrict__ partial,
        const float4* __restrict__ bbox, const float4* __restrict__ anch,
        float4* __restrict__ boxes) {
    const int b = blockIdx.x >> 5;
    const int i = ((blockIdx.x & 31) << 8) + threadIdx.x;
    const uint32_t m = min(meta[MT_CNT(b)], (uint32_t)CAND_CAP);
    if ((uint32_t)i >= m) return;
    const int njc = (int)((m + 511) >> 9);
    uint32_t rank = 0;
    for (int jc = 0; jc < njc; ++jc)
        rank += partial[(((size_t)(b * 16 + jc)) << 13) + i];
    if (rank >= (uint32_t)K_PRE) return;
    const uint64_t ki = cand[(size_t)b * CAND_CAP + i];
    const uint32_t n = ~((uint32_t)ki);
    const float4 a = anch[(size_t)b * NN + n];
    const float4 d = bbox[(size_t)b * NN + n];
    float h = a.z - a.x, w = a.w - a.y;
    const float cy0 = a.x + 0.5f * h + d.x * 0.1f * h;
    const float cx0 = a.y + 0.5f * w + d.y * 0.1f * w;
    h = h * expf(d.z * 0.2f);
    w = w * expf(d.w * 0.2f);
    float4 o;
    o.x = fminf(fmaxf(cy0 - 0.5f * h, 0.0f), 1.0f);
    o.y = fminf(fmaxf(cx0 - 0.5f * w, 0.0f), 1.0f);
    o.z = fminf(fmaxf(cy0 + 0.5f * h, 0.0f), 1.0f);
    o.w = fminf(fmaxf(cx0 + 0.5f * w, 0.0f), 1.0f);
    boxes[(size_t)b * K_PRE + rank] = o;
}

__global__ __launch_bounds__(256) void k_matrix(const float4* __restrict__ boxes,
                                                uint32_t* __restrict__ mask) {
    const int blk = blockIdx.x;
    const int b = blk >> 10;
    const int tile = blk & 1023;
    const int ti = tile >> 5, tj = tile & 31;
    __shared__ float4 rb[64], cb[64];
    __shared__ uint32_t wbits[128];
    const float4* bx = boxes + (size_t)b * K_PRE;
    const int t = threadIdx.x;
    if (t < 64) rb[t] = bx[ti * 64 + t];
    else if (t < 128) cb[t - 64] = bx[tj * 64 + (t - 64)];
    if (t < 128) wbits[t] = 0;
    __syncthreads();
    const int r = t >> 2;
    const int cq = t & 3;
    const float4 a = rb[r];
    const float areaA = (a.z - a.x) * (a.w - a.y);
    uint32_t bits = 0;
#pragma unroll
    for (int jj = 0; jj < 16; ++jj) {
        const float4 cc = cb[cq * 16 + jj];
        const float yy1 = fmaxf(a.x, cc.x), xx1 = fmaxf(a.y, cc.y);
        const float yy2 = fminf(a.z, cc.z), xx2 = fminf(a.w, cc.w);
        const float inter = fmaxf(yy2 - yy1, 0.0f) * fmaxf(xx2 - xx1, 0.0f);
        const float areaC = (cc.z - cc.x) * (cc.w - cc.y);
        const float uni = fmaxf(areaA + areaC - inter, 1e-8f);
        if (inter / uni > NMS_THR) bits |= (1u << jj);
    }
    atomicOr(&wbits[r * 2 + (cq >> 1)], bits << ((cq & 1) * 16));
    __syncthreads();
    if (t < 128) {
        const int rr = t >> 1, ww = t & 1;
        mask[((size_t)b * PREFIX + ti * 64 + rr) * 64 + tj * 2 + ww] = wbits[rr * 2 + ww];
    }
}

// Conflict extraction: mask is symmetric, so "row i has an earlier suppressor"
// == "row i has a set bit below its diagonal". 1 thread per row; pack up to 5
// suppressor indices (12b each) + count into a u64. Conflicted bitmap written
// per-wave via ballot (disjoint words -> no atomics, no zeroing).
__global__ __launch_bounds__(256) void k_conflict(const uint32_t* __restrict__ mask,
        uint64_t* __restrict__ sinfo, uint32_t* __restrict__ cbm) {
    const int b = blockIdx.x >> 3;
    const int s = blockIdx.x & 7;
    const int i = (s << 8) + threadIdx.x;
    const uint4* row4 = (const uint4*)(mask + ((size_t)b * PREFIX + i) * 64);
    const int iw = i >> 5;
    const uint32_t tailmask = ((uint32_t)1 << (i & 31)) - 1u;
    uint32_t cnt = 0;
    uint64_t packed = 0;
    for (int c = 0; c <= (iw >> 2); ++c) {
        const uint4 q = row4[c];
        uint32_t ws[4] = {q.x, q.y, q.z, q.w};
#pragma unroll
        for (int k = 0; k < 4; ++k) {
            const int w = c * 4 + k;
            uint32_t bits = ws[k];
            if (w > iw) bits = 0;
            else if (w == iw) bits &= tailmask;
            while (bits) {
                const int bp = __ffs(bits) - 1;
                bits &= bits - 1;
                if (cnt < 5) packed |= (uint64_t)(uint32_t)(w * 32 + bp) << (12 * cnt);
                ++cnt;
            }
        }
    }
    packed |= (uint64_t)(cnt <= 5 ? cnt : 6) << 60;   // 6 = heavy (rescan row)
    sinfo[(size_t)b * PREFIX + i] = packed;
    const unsigned long long bm = __ballot(cnt != 0);
    const int wv = threadIdx.x >> 6;
    const int lid = threadIdx.x & 63;
    if (lid == 0) cbm[(size_t)b * 64 + (s << 3) + wv * 2] = (uint32_t)bm;
    else if (lid == 1) cbm[(size_t)b * 64 + (s << 3) + wv * 2 + 1] = (uint32_t)(bm >> 32);
}

// Greedy resolution: taken-bitmap in lane registers (lane l = word l).
// Non-conflicted rows are unconditionally taken; only conflicted rows (~3%)
// are resolved serially in ascending order using readlane on the taken words.
// Emit first min(1000, total) taken rows (ascending == greedy order).
__global__ __launch_bounds__(64) void k_greedy(const uint32_t* __restrict__ mask,
        const uint64_t* __restrict__ sinfo, const uint32_t* __restrict__ cbm,
        uint32_t* meta, uint32_t* __restrict__ kept_idx) {
    __shared__ uint32_t conf_rows[PREFIX];
    __shared__ uint32_t ncf_s;
    const int b = blockIdx.x;
    const int lane = threadIdx.x;
    const uint32_t cw = cbm[(size_t)b * 64 + lane];
    uint32_t taken = 0xFFFFFFFFu;

    // compact conflicted row indices (ascending)
    const uint32_t pc = (uint32_t)__popc(cw);
    uint32_t pref = pc;
    for (int d = 1; d < 64; d <<= 1) {
        const uint32_t v = __shfl_up(pref, d);
        if (lane >= d) pref += v;
    }
    const uint32_t ncf = __shfl(pref, 63);
    uint32_t idx = pref - pc;
    uint32_t tm = cw;
    while (tm) {
        const int q = __ffs(tm) - 1;
        tm &= tm - 1;
        conf_rows[idx] = (uint32_t)(lane * 32 + q);
        ++idx;
    }
    if (lane == 0) ncf_s = ncf;
    __syncthreads();

    // prefetch first 256 (i, info) pairs into registers
    uint32_t r_i[4], r_lo[4], r_hi[4];
#pragma unroll
    for (int r = 0; r < 4; ++r) {
        const uint32_t k = (uint32_t)(r * 64 + lane);
        const uint32_t ri = (k < ncf) ? conf_rows[k] : 0;
        const uint64_t nf = (k < ncf) ? sinfo[(size_t)b * PREFIX + ri] : 0ull;
        r_i[r] = ri;
        r_lo[r] = (uint32_t)nf;
        r_hi[r] = (uint32_t)(nf >> 32);
    }

    const uint32_t* mbase = mask + (size_t)b * PREFIX * 64;

    // serial resolve (wave-uniform), prefetched segments
#pragma unroll
    for (int seg = 0; seg < 4; ++seg) {
        const uint32_t segbase = (uint32_t)(seg * 64);
        if (segbase < ncf) {
            const uint32_t segcnt = min(64u, ncf - segbase);
            for (uint32_t k2 = 0; k2 < segcnt; ++k2) {
                const uint32_t i  = __builtin_amdgcn_readlane(r_i[seg], (int)k2);
                const uint32_t lo = __builtin_amdgcn_readlane(r_lo[seg], (int)k2);
                const uint32_t hi = __builtin_amdgcn_readlane(r_hi[seg], (int)k2);
                const uint32_t cnt = hi >> 28;
                bool dropped = false;
                if (cnt == 6) {   // heavy: rescan row lower-triangle vs taken
                    const uint32_t* row = mbase + (size_t)i * 64;
                    const int iw = i >> 5;
                    for (int w = 0; w <= iw; ++w) {
                        uint32_t bits = row[w];
                        if (w == iw) bits &= (((uint32_t)1 << (i & 31)) - 1u);
                        const uint32_t tk = __builtin_amdgcn_readlane(taken, w);
                        if (bits & tk) { dropped = true; break; }
                    }
                } else {
                    uint64_t p = ((uint64_t)hi << 32) | lo;
                    for (uint32_t c = 0; c < cnt; ++c) {
                        const uint32_t j = (uint32_t)(p & 0xFFFu);
                        p >>= 12;
                        const uint32_t tk = __builtin_amdgcn_readlane(taken, (int)(j >> 5));
                        if ((tk >> (j & 31)) & 1u) dropped = true;
                    }
                }
                if (dropped) {
                    const int w = (int)(i >> 5);
                    if (lane == w) taken &= ~((uint32_t)1 << (i & 31));
                }
            }
        }
    }
    // tail (>256 conflicted rows): uniform slow path, correctness fallback
    for (uint32_t k = 256; k < ncf; ++k) {
        const uint32_t i = conf_rows[k];
        const uint64_t nf = sinfo[(size_t)b * PREFIX + i];
        const uint32_t cnt = (uint32_t)(nf >> 60);
        bool dropped = false;
        if (cnt == 6) {
            const uint32_t* row = mbase + (size_t)i * 64;
            const int iw = i >> 5;
            for (int w = 0; w <= iw; ++w) {
                uint32_t bits = row[w];
                if (w == iw) bits &= (((uint32_t)1 << (i & 31)) - 1u);
                const uint32_t tk = __builtin_amdgcn_readlane(taken, w);
                if (bits & tk) { dropped = true; break; }
            }
        } else {
            uint64_t p = nf;
            for (uint32_t c = 0; c < cnt; ++c) {
                const uint32_t j = (uint32_t)(p & 0xFFFu);
                p >>= 12;
                const uint32_t tk = __builtin_amdgcn_readlane(taken, (int)(j >> 5));
                if ((tk >> (j & 31)) & 1u) dropped = true;
            }
        }
        if (dropped) {
            const int w = (int)(i >> 5);
            if (lane == w) taken &= ~((uint32_t)1 << (i & 31));
        }
    }

    // emit: ascending taken rows, rank < NPROP
    const uint32_t tpc = (uint32_t)__popc(taken);
    uint32_t tpref = tpc;
    for (int d = 1; d < 64; d <<= 1) {
        const uint32_t v = __shfl_up(tpref, d);
        if (lane >= d) tpref += v;
    }
    const uint32_t total = __shfl(tpref, 63);
    uint32_t rank = tpref - tpc;
    uint32_t w = taken;
    while (w) {
        const int q = __ffs(w) - 1;
        w &= w - 1;
        if (rank < (uint32_t)NPROP)
            kept_idx[(size_t)b * NPROP + rank] = (uint32_t)(lane * 32 + q);
        ++rank;
    }
    if (lane == 0) meta[MT_KEPT + b] = min(total, (uint32_t)NPROP);
}

__global__ __launch_bounds__(1024) void k_finish(const float4* __restrict__ boxes,
        uint32_t* meta, uint32_t* kept_idx, float4* __restrict__ out) {
    const int b = blockIdx.x;
    const float4* bx = boxes + (size_t)b * K_PRE;
    __shared__ float4 kb[NPROP];
    __shared__ uint32_t sflag;
    uint32_t kept = meta[MT_KEPT + b];
    if (kept < NPROP) {
        for (uint32_t k = threadIdx.x; k < kept; k += 1024)
            kb[k] = bx[kept_idx[(size_t)b * NPROP + k]];
        __syncthreads();
        for (int i = PREFIX; i < K_PRE && kept < NPROP; ++i) {
            if (threadIdx.x == 0) sflag = 0;
            __syncthreads();
            const float4 c = bx[i];
            const float areaC = (c.z - c.x) * (c.w - c.y);
            bool sup = false;
            for (uint32_t k = threadIdx.x; k < kept; k += 1024) {
                const float4 a = kb[k];
                const float yy1 = fmaxf(c.x, a.x), xx1 = fmaxf(c.y, a.y);
                const float yy2 = fminf(c.z, a.z), xx2 = fminf(c.w, a.w);
                const float inter = fmaxf(yy2 - yy1, 0.0f) * fmaxf(xx2 - xx1, 0.0f);
                const float areaA = (a.z - a.x) * (a.w - a.y);
                const float uni = fmaxf(areaC + areaA - inter, 1e-8f);
                if (inter / uni > NMS_THR) { sup = true; break; }
            }
            if (sup) atomicOr(&sflag, 1u);
            __syncthreads();
            if (sflag == 0) {
                if (threadIdx.x == 0) {
                    kept_idx[(size_t)b * NPROP + kept] = (uint32_t)i;
                    kb[kept] = c;
                }
                ++kept;
            }
            __syncthreads();
        }
        if (threadIdx.x == 0) meta[MT_KEPT + b] = kept;
    }
    __syncthreads();
    for (uint32_t k = threadIdx.x; k < NPROP; k += 1024) {
        float4 v = make_float4(0.f, 0.f, 0.f, 0.f);
        if (k < kept) v = bx[kept_idx[(size_t)b * NPROP + k]];
        out[(size_t)b * NPROP + k] = v;
    }
}

extern "C" void kernel_launch(void* const* d_in, const int* in_sizes, int n_in,
                              void* d_out, int out_size, void* d_ws, size_t ws_size,
                              hipStream_t stream) {
    const float4* probs4 = (const float4*)d_in[0];
    const float4* bbox   = (const float4*)d_in[1];
    const float4* anch   = (const float4*)d_in[2];
    char* ws = (char*)d_ws;
    if (ws_size < (size_t)WS_NEED) return;
    uint32_t* hist1 = (uint32_t*)(ws + HIST1_OFF);
    uint32_t* hist2 = (uint32_t*)(ws + HIST2_OFF);
    uint32_t* meta  = (uint32_t*)(ws + META_OFF);
    uint64_t* cand  = (uint64_t*)(ws + CAND_OFF);
    float4*   boxes = (float4*)(ws + BOXES_OFF);
    uint32_t* mask  = (uint32_t*)(ws + MASK_OFF);
    uint32_t* kidx  = (uint32_t*)(ws + KIDX_OFF);
    uint32_t* partial = (uint32_t*)(ws + MASK_OFF);  // reuse: consumed before k_matrix writes
    uint64_t* sinfo = (uint64_t*)(ws + HIST1_OFF);   // reuse: hist1 dead after k_thresh
    uint32_t* cbm   = (uint32_t*)(ws + HIST2_OFF);   // reuse: hist2 dead after k_thresh2

    k_zero<<<dim3((HZERO + CZERO + 255) / 256), dim3(256), 0, stream>>>(hist1, (uint32_t*)cand);
    k_hist<<<dim3(512), dim3(256), 0, stream>>>(probs4, hist1);
    k_thresh<<<dim3(BATCH), dim3(256), 0, stream>>>(hist1, meta);
    k_hist2<<<dim3(2048), dim3(256), 0, stream>>>(probs4, meta, hist2);
    k_thresh2<<<dim3(BATCH), dim3(256), 0, stream>>>(hist2, meta);
    k_compact<<<dim3(2048), dim3(256), 0, stream>>>(probs4, meta, meta, cand);
    k_rank<<<dim3(BATCH * 128), dim3(256), 0, stream>>>(cand, meta, partial);
    k_decode<<<dim3(BATCH * 32), dim3(256), 0, stream>>>(cand, meta, partial, bbox, anch, boxes);
    k_matrix<<<dim3(BATCH * 1024), dim3(256), 0, stream>>>(boxes, mask);
    k_conflict<<<dim3(BATCH * 8), dim3(256), 0, stream>>>(mask, sinfo, cbm);
    k_greedy<<<dim3(BATCH), dim3(64), 0, stream>>>(mask, sinfo, cbm, meta, kidx);
    k_finish<<<dim3(BATCH), dim3(1024), 0, stream>>>(boxes, meta, kidx, (float4*)d_out);
}